// Round 9
// baseline (438.184 us; speedup 1.0000x reference)
//
#include <hip/hip_runtime.h>

#define N_NODES 50000
#define N_EDGES 800000
#define ET (N_EDGES + N_NODES)   // 850000 incl. self loops
#define HEADS 8
#define NPAD 50048               // 782 blocks * 64 nodes
#define SCAN_NB 196              // ceil(50000/256)
#define CAP 96                   // LDS-cached edges per node (deg>CAP -> recompute)

typedef __attribute__((ext_vector_type(8))) _Float16 half8;
typedef __attribute__((ext_vector_type(2))) _Float16 half2v;
typedef __attribute__((ext_vector_type(4))) float f32x4;

// ---------- edge-index layout detection (int32 vs int64 storage) ----------
__global__ void k_detect(const int* __restrict__ ei, int* __restrict__ flag){
  if (blockIdx.x == 0 && threadIdx.x == 0){
    int zeros = 0;
    for (int i = 0; i < 64; i++){
      if (ei[2*i + 1] == 0) zeros++;
    }
    *flag = (zeros >= 60) ? 1 : 0;   // 1 => int64 little-endian layout
  }
}

__device__ __forceinline__ int edge_src(const int* ei, int e, int is64){
  if (e >= N_EDGES) return e - N_EDGES;          // self loop
  return is64 ? ei[2*e] : ei[e];
}
__device__ __forceinline__ int edge_dst(const int* ei, int e, int is64){
  if (e >= N_EDGES) return e - N_EDGES;          // self loop
  return is64 ? ei[2*(N_EDGES + e)] : ei[N_EDGES + e];
}

// ---------------- CSR build ----------------
__global__ void k_zero2(int* __restrict__ a, int* __restrict__ b, int n){
  int i = blockIdx.x*blockDim.x + threadIdx.x;
  if (i < n){ a[i] = 0; b[i] = 0; }
}

__global__ void k_degree(const int* __restrict__ ei, int* __restrict__ deg,
                         const int* __restrict__ flag){
  int e = blockIdx.x*blockDim.x + threadIdx.x;
  if (e >= ET) return;
  int is64 = *flag;
  int d = edge_dst(ei, e, is64);
  atomicAdd(&deg[d], 1);
}

// ---- 3-stage scan ----
__global__ void k_scan_part(const int* __restrict__ deg, int* __restrict__ loc,
                            int* __restrict__ part){
  __shared__ int lds[256];
  int t = threadIdx.x, i = blockIdx.x*256 + t;
  int v = (i < N_NODES) ? deg[i] : 0;
  lds[t] = v;
  __syncthreads();
  for (int off = 1; off < 256; off <<= 1){
    int x = (t >= off) ? lds[t - off] : 0;
    __syncthreads();
    lds[t] += x;
    __syncthreads();
  }
  if (i < N_NODES) loc[i] = lds[t] - v;          // local exclusive
  if (t == 255) part[blockIdx.x] = lds[255];
}

__global__ void k_scan_carry(int* __restrict__ part, int* __restrict__ carry){
  __shared__ int lds[256];
  int t = threadIdx.x;
  int v = (t < SCAN_NB) ? part[t] : 0;
  lds[t] = v;
  __syncthreads();
  for (int off = 1; off < 256; off <<= 1){
    int x = (t >= off) ? lds[t - off] : 0;
    __syncthreads();
    lds[t] += x;
    __syncthreads();
  }
  if (t < SCAN_NB) carry[t] = lds[t] - v;        // exclusive over blocks
}

__global__ void k_scan_add(const int* __restrict__ loc, const int* __restrict__ carry,
                           int* __restrict__ row_ptr){
  int i = blockIdx.x*blockDim.x + threadIdx.x;
  if (i < N_NODES) row_ptr[i] = loc[i] + carry[i >> 8];
  if (i == 0) row_ptr[N_NODES] = ET;
}

__global__ void k_fill(const int* __restrict__ ei, const int* __restrict__ row_ptr,
                       int* __restrict__ cnt, int* __restrict__ col,
                       const int* __restrict__ flag){
  int e = blockIdx.x*blockDim.x + threadIdx.x;
  if (e >= ET) return;
  int is64 = *flag;
  int s = edge_src(ei, e, is64);
  int d = edge_dst(ei, e, is64);
  int pos = atomicAdd(&cnt[d], 1);
  col[row_ptr[d] + pos] = s;
}

// ---------------- merged weight prep (one launch) ----------------
// blocks [0,256): W2 pack; [256,320): W1 pack; [320,324): wtilde
__global__ void k_wprep(const float* __restrict__ W1, const float* __restrict__ W2,
                        const float* __restrict__ as2, const float* __restrict__ ad2,
                        _Float16* __restrict__ Bp1, _Float16* __restrict__ Bp,
                        float* __restrict__ ws2, float* __restrict__ wd2){
  int b = blockIdx.x;
  int t_ = threadIdx.x;
  if (b < 256){
    int t = b*256 + t_;
    int j = t & 7, lane = (t >> 3) & 63, nt = (t >> 9) & 3, kt = t >> 11;
    int k = kt*32 + (lane >> 4)*8 + j;
    int c = nt*16 + (lane & 15);
    int h = k >> 7, kk = k & 127;
    Bp[t] = (_Float16)(0.125f * W2[kk*512 + h*64 + c]);
  } else if (b < 320){
    int t = (b - 256)*256 + t_;
    int j = t & 7, lane = (t >> 3) & 63, nt = (t >> 9) & 7, kt = t >> 12;
    int k = kt*32 + (lane >> 4)*8 + j;
    int c = nt*16 + (lane & 15);
    Bp1[t] = (_Float16)W1[k*128 + c];
  } else {
    int t = (b - 320)*256 + t_;
    int k = t >> 3, h = t & 7;
    float s = 0.f, d = 0.f;
    for (int dd = 0; dd < 64; dd++){
      float w = W2[k*512 + h*64 + dd];
      s += w * as2[h*64 + dd];
      d += w * ad2[h*64 + dd];
    }
    ws2[h*128 + k] = s;
    wd2[h*128 + k] = d;
  }
}

// ---------------- layer 1 GEMM via MFMA: h1[N,128] = x @ W1 (fp16 out) ----------------
__global__ void __launch_bounds__(256) k_gemm1_mfma(
    const float* __restrict__ x, const _Float16* __restrict__ Bp1,
    _Float16* __restrict__ h1){
  int tid = threadIdx.x;
  int lane = tid & 63, wv = tid >> 6;
  int n0 = blockIdx.x*64 + wv*16;
  int rowA = n0 + (lane & 15);
  int koff = (lane >> 4)*8;
  const float* xr = x + (size_t)rowA*128 + koff;
  f32x4 acc[8];
  #pragma unroll
  for (int i = 0; i < 8; i++) acc[i] = (f32x4){0.f,0.f,0.f,0.f};
  bool inb = (rowA < N_NODES);
  #pragma unroll
  for (int kt = 0; kt < 4; kt++){
    half8 af;
    if (inb){
      float4 a0 = *(const float4*)(xr + kt*32);
      float4 a1 = *(const float4*)(xr + kt*32 + 4);
      af = (half8){(_Float16)a0.x,(_Float16)a0.y,(_Float16)a0.z,(_Float16)a0.w,
                   (_Float16)a1.x,(_Float16)a1.y,(_Float16)a1.z,(_Float16)a1.w};
    } else {
      af = (half8){0,0,0,0,0,0,0,0};
    }
    #pragma unroll
    for (int nt = 0; nt < 8; nt++){
      half8 bf = *(const half8*)(Bp1 + (((kt*8 + nt)*64 + lane) << 3));
      acc[nt] = __builtin_amdgcn_mfma_f32_16x16x32_f16(af, bf, acc[nt], 0, 0, 0);
    }
  }
  int r0 = n0 + (lane >> 4)*4;     // C/D: col=lane&15, row=(lane>>4)*4+reg  [m89]
  #pragma unroll
  for (int nt = 0; nt < 8; nt++){
    int c = nt*16 + (lane & 15);
    #pragma unroll
    for (int r = 0; r < 4; r++){
      int n = r0 + r;
      if (n < N_NODES) h1[(size_t)n*128 + c] = (_Float16)acc[nt][r];
    }
  }
}

// ---- alpha logits, layer 1 ----
__global__ void k_alpha1(const _Float16* __restrict__ h1, const float* __restrict__ as1,
                         const float* __restrict__ ad1,
                         float* __restrict__ als, float* __restrict__ ald){
  int t = blockIdx.x*blockDim.x + threadIdx.x;
  if (t >= N_NODES*8) return;
  int n = t >> 3, hh = t & 7;
  const half2v* hp = (const half2v*)(h1 + (size_t)n*128 + hh*16);
  float s = 0.f, d = 0.f;
  #pragma unroll
  for (int i = 0; i < 8; i++){
    half2v v = hp[i];
    float vx = (float)v.x, vy = (float)v.y;
    s += vx*as1[hh*16 + 2*i] + vy*as1[hh*16 + 2*i + 1];
    d += vx*ad1[hh*16 + 2*i] + vy*ad1[hh*16 + 2*i + 1];
  }
  als[t] = s; ald[t] = d;
}

// ---- alpha logits, layer 2 ----
__global__ void k_alpha2(const _Float16* __restrict__ hr, const float* __restrict__ ws2,
                         const float* __restrict__ wd2,
                         float* __restrict__ als, float* __restrict__ ald){
  int t = blockIdx.x*blockDim.x + threadIdx.x;
  if (t >= N_NODES*8) return;
  int n = t >> 3, hh = t & 7;
  const half2v* hp = (const half2v*)(hr + (size_t)n*128);
  float s = 0.f, d = 0.f;
  #pragma unroll 16
  for (int i = 0; i < 64; i++){
    half2v v = hp[i];
    float vx = (float)v.x, vy = (float)v.y;
    s += vx*ws2[hh*128 + 2*i] + vy*ws2[hh*128 + 2*i + 1];
    d += vx*wd2[hh*128 + 2*i] + vy*wd2[hh*128 + 2*i + 1];
  }
  als[t] = s; ald[t] = d;
}

// ===== layer 1: two-phase softmax+agg, LDS logit cache, fp32 acc =====
// phase 1: item-parallel (64 (edge,head)/iter) leaky logits -> LDS fp16 + l=sum(exp)
// phase 2: lane owns channels {2L,2L+1}, head hh0=L>>3; w = exp(logit)*inv from LDS
__global__ void k_attn_agg1(const _Float16* __restrict__ h1,
    const float* __restrict__ als, const float* __restrict__ ald,
    const int* __restrict__ row_ptr, const int* __restrict__ col,
    const float* __restrict__ bias, _Float16* __restrict__ hr){
  __shared__ _Float16 ew_s[4][CAP*8];
  int tid = threadIdx.x;
  int wv = tid >> 6, lane = tid & 63;
  int n = blockIdx.x*4 + wv;
  if (n >= N_NODES) return;
  int beg = row_ptr[n], end = row_ptr[n+1];
  int items = (end - beg)*8;
  int h = lane & 7;
  float ad = ald[n*8 + h];
  _Float16* es = ew_s[wv];
  float l = 0.f;
  for (int it = lane; it < items; it += 64){
    int s = col[beg + (it >> 3)];
    float a = als[s*8 + h] + ad;
    a = (a > 0.f) ? a : 0.2f*a;
    if (it < CAP*8) es[it] = (_Float16)a;
    l += __expf(a);
  }
  l += __shfl_xor(l, 8, 64);
  l += __shfl_xor(l, 16, 64);
  l += __shfl_xor(l, 32, 64);
  float inv = 1.f / (l + 1e-16f);
  __syncthreads();     // phase1 is short (deg/8 iters); phase2 below unsynced
  int hh0 = lane >> 3;
  float invh = __shfl(inv, hh0, 64);
  float adh = ald[n*8 + hh0];
  const half2v* h2p = (const half2v*)h1;
  float ax = 0.f, ay = 0.f;
  int deg = end - beg;
  int j = 0;
  for (; j + 3 < deg; j += 4){
    int s0 = col[beg + j], s1 = col[beg + j + 1];
    int s2 = col[beg + j + 2], s3 = col[beg + j + 3];
    float a0, a1, a2, a3;
    if (j + 3 < CAP){
      a0 = (float)es[j*8 + hh0];       a1 = (float)es[(j+1)*8 + hh0];
      a2 = (float)es[(j+2)*8 + hh0];   a3 = (float)es[(j+3)*8 + hh0];
    } else {
      a0 = als[s0*8 + hh0] + adh; a0 = (a0 > 0.f) ? a0 : 0.2f*a0;
      a1 = als[s1*8 + hh0] + adh; a1 = (a1 > 0.f) ? a1 : 0.2f*a1;
      a2 = als[s2*8 + hh0] + adh; a2 = (a2 > 0.f) ? a2 : 0.2f*a2;
      a3 = als[s3*8 + hh0] + adh; a3 = (a3 > 0.f) ? a3 : 0.2f*a3;
    }
    float w0 = __expf(a0)*invh, w1 = __expf(a1)*invh;
    float w2 = __expf(a2)*invh, w3 = __expf(a3)*invh;
    half2v v0 = h2p[(size_t)s0*64 + lane];
    half2v v1 = h2p[(size_t)s1*64 + lane];
    half2v v2 = h2p[(size_t)s2*64 + lane];
    half2v v3 = h2p[(size_t)s3*64 + lane];
    ax += w0*(float)v0.x + w1*(float)v1.x + w2*(float)v2.x + w3*(float)v3.x;
    ay += w0*(float)v0.y + w1*(float)v1.y + w2*(float)v2.y + w3*(float)v3.y;
  }
  for (; j < deg; j++){
    int s = col[beg + j];
    float a;
    if (j < CAP) a = (float)es[j*8 + hh0];
    else { a = als[s*8 + hh0] + adh; a = (a > 0.f) ? a : 0.2f*a; }
    float w = __expf(a)*invh;
    half2v v = h2p[(size_t)s*64 + lane];
    ax += w*(float)v.x; ay += w*(float)v.y;
  }
  float2 bb = ((const float2*)bias)[lane];
  float o0 = fmaxf(ax + bb.x, 0.f);
  float o1 = fmaxf(ay + bb.y, 0.f);
  half2v oo; oo.x = (_Float16)o0; oo.y = (_Float16)o1;
  ((half2v*)hr)[(size_t)n*64 + lane] = oo;
}

// ===== layer 2: two-phase softmax+agg, LDS logit cache, fp16 pk acc =====
// phase 2 lane mapping: head hq=lane&7 (own softmax state), channels gq*16..+15;
// normalized fp16 weights (<=1) -> v_pk_fma_f16 accumulation (r6-proven).
__global__ void k_attn_agg2(const _Float16* __restrict__ hr,
    const float* __restrict__ als, const float* __restrict__ ald,
    const int* __restrict__ row_ptr, const int* __restrict__ col,
    _Float16* __restrict__ aggb){
  __shared__ _Float16 ew_s[4][CAP*8];
  int tid = threadIdx.x;
  int wv = tid >> 6, lane = tid & 63;
  int n = blockIdx.x*4 + wv;
  if (n >= N_NODES) return;
  int beg = row_ptr[n], end = row_ptr[n+1];
  int items = (end - beg)*8;
  int h = lane & 7;
  float ad = ald[n*8 + h];
  _Float16* es = ew_s[wv];
  float l = 0.f;
  for (int it = lane; it < items; it += 64){
    int s = col[beg + (it >> 3)];
    float a = als[s*8 + h] + ad;
    a = (a > 0.f) ? a : 0.2f*a;
    if (it < CAP*8) es[it] = (_Float16)a;
    l += __expf(a);
  }
  l += __shfl_xor(l, 8, 64);
  l += __shfl_xor(l, 16, 64);
  l += __shfl_xor(l, 32, 64);
  float inv = 1.f / (l + 1e-16f);   // for head hq = lane&7
  __syncthreads();
  int hq = lane & 7, gq = lane >> 3;
  half2v acc[8];
  #pragma unroll
  for (int i = 0; i < 8; i++) acc[i] = (half2v){(_Float16)0.f, (_Float16)0.f};
  int deg = end - beg;
  int j = 0;
  for (; j + 1 < deg; j += 2){
    int s0 = col[beg + j], s1 = col[beg + j + 1];
    float a0, a1;
    if (j + 1 < CAP){
      a0 = (float)es[j*8 + hq];
      a1 = (float)es[(j+1)*8 + hq];
    } else {
      a0 = als[s0*8 + hq] + ad; a0 = (a0 > 0.f) ? a0 : 0.2f*a0;
      a1 = als[s1*8 + hq] + ad; a1 = (a1 > 0.f) ? a1 : 0.2f*a1;
    }
    float w0 = __expf(a0)*inv, w1 = __expf(a1)*inv;
    _Float16 w0h = (_Float16)w0, w1h = (_Float16)w1;
    half2v w0p = {w0h, w0h}, w1p = {w1h, w1h};
    const _Float16* p0 = hr + (size_t)s0*128 + gq*16;
    const _Float16* p1 = hr + (size_t)s1*128 + gq*16;
    half8 va0 = *(const half8*)p0, vb0 = *(const half8*)(p0 + 8);
    half8 va1 = *(const half8*)p1, vb1 = *(const half8*)(p1 + 8);
    #pragma unroll
    for (int k = 0; k < 4; k++){
      acc[k]   += w0p * (half2v){va0[2*k], va0[2*k+1]};
      acc[k+4] += w0p * (half2v){vb0[2*k], vb0[2*k+1]};
      acc[k]   += w1p * (half2v){va1[2*k], va1[2*k+1]};
      acc[k+4] += w1p * (half2v){vb1[2*k], vb1[2*k+1]};
    }
  }
  for (; j < deg; j++){
    int s = col[beg + j];
    float a;
    if (j < CAP) a = (float)es[j*8 + hq];
    else { a = als[s*8 + hq] + ad; a = (a > 0.f) ? a : 0.2f*a; }
    float w = __expf(a)*inv;
    _Float16 wh = (_Float16)w;
    half2v wp = {wh, wh};
    const _Float16* p = hr + (size_t)s*128 + gq*16;
    half8 va = *(const half8*)p, vb = *(const half8*)(p + 8);
    #pragma unroll
    for (int k = 0; k < 4; k++){
      acc[k]   += wp * (half2v){va[2*k], va[2*k+1]};
      acc[k+4] += wp * (half2v){vb[2*k], vb[2*k+1]};
    }
  }
  _Float16* ar = aggb + (size_t)n*1024 + hq*128 + gq*16;
  half8 oa, ob;
  #pragma unroll
  for (int k = 0; k < 4; k++){
    oa[2*k] = acc[k].x;   oa[2*k+1] = acc[k].y;
    ob[2*k] = acc[k+4].x; ob[2*k+1] = acc[k+4].y;
  }
  *(half8*)ar = oa;
  *(half8*)(ar + 8) = ob;
}

// ------- layer-2 output GEMM via MFMA f16: out = agg[N,1024] @ Wt[1024,64] + b2 -------
__global__ void __launch_bounds__(256) k_gemm_out_mfma(
    const _Float16* __restrict__ aggb, const _Float16* __restrict__ Bp,
    const float* __restrict__ b2, float* __restrict__ outp){
  int tid = threadIdx.x;
  int lane = tid & 63, wv = tid >> 6;
  int n0 = blockIdx.x*64 + wv*16;
  int rowA = n0 + (lane & 15);
  const _Float16* arow = aggb + (size_t)rowA*1024 + (lane >> 4)*8;
  f32x4 acc[4];
  #pragma unroll
  for (int i = 0; i < 4; i++) acc[i] = (f32x4){0.f,0.f,0.f,0.f};
  for (int kt = 0; kt < 32; kt++){
    half8 af = *(const half8*)(arow + kt*32);
    #pragma unroll
    for (int nt = 0; nt < 4; nt++){
      half8 bf = *(const half8*)(Bp + (((kt*4 + nt)*64 + lane) << 3));
      acc[nt] = __builtin_amdgcn_mfma_f32_16x16x32_f16(af, bf, acc[nt], 0, 0, 0);
    }
  }
  int r0 = n0 + (lane >> 4)*4;     // C/D: col=lane&15, row=(lane>>4)*4+reg  [m89]
  #pragma unroll
  for (int nt = 0; nt < 4; nt++){
    int c = nt*16 + (lane & 15);
    float bb = b2[c];
    #pragma unroll
    for (int r = 0; r < 4; r++){
      int n = r0 + r;
      if (n < N_NODES) outp[n*64 + c] = acc[nt][r] + bb;
    }
  }
}

extern "C" void kernel_launch(void* const* d_in, const int* in_sizes, int n_in,
                              void* d_out, int out_size, void* d_ws, size_t ws_size,
                              hipStream_t stream){
  const float* x   = (const float*)d_in[0];
  const int*   ei  = (const int*)d_in[1];
  const float* W1  = (const float*)d_in[2];
  const float* as1 = (const float*)d_in[3];
  const float* ad1 = (const float*)d_in[4];
  const float* b1  = (const float*)d_in[5];
  const float* W2  = (const float*)d_in[6];
  const float* as2 = (const float*)d_in[7];
  const float* ad2 = (const float*)d_in[8];
  const float* b2  = (const float*)d_in[9];
  float* outp = (float*)d_out;

  char* p = (char*)d_ws;
  auto alloc = [&](size_t bytes) -> void* {
    void* r = (void*)p;
    p += (bytes + 255) & ~(size_t)255;
    return r;
  };
  // aggb (102.5 MB) also hosts h1 (12.8 MB) — h1 dead before k_attn_agg2 writes.
  _Float16* aggb = (_Float16*)alloc((size_t)NPAD*1024*2);
  _Float16* h1  = aggb;                                          // [N,128] fp16
  _Float16* hr  = (_Float16*)alloc((size_t)N_NODES*128*2);       // [N,128] fp16
  float* als1 = (float*)alloc((size_t)N_NODES*8*4);
  float* ald1 = (float*)alloc((size_t)N_NODES*8*4);
  float* als2 = (float*)alloc((size_t)N_NODES*8*4);
  float* ald2 = (float*)alloc((size_t)N_NODES*8*4);
  int* row_ptr = (int*)alloc((size_t)(N_NODES+1)*4);
  int* deg  = (int*)alloc((size_t)N_NODES*4);
  int* cnt  = (int*)alloc((size_t)N_NODES*4);
  int* col  = (int*)alloc((size_t)ET*4);
  int* loc  = (int*)alloc((size_t)N_NODES*4);
  int* part = (int*)alloc(256*4);
  int* carry= (int*)alloc(256*4);
  int* flag = (int*)alloc(256);
  float* ws2 = (float*)alloc(1024*4);
  float* wd2 = (float*)alloc(1024*4);
  _Float16* Bp1 = (_Float16*)alloc((size_t)16384*2);
  _Float16* Bp  = (_Float16*)alloc((size_t)65536*2);

  dim3 b256(256);
  // edge-index layout probe + CSR build
  k_detect<<<1, 64, 0, stream>>>(ei, flag);
  k_zero2<<<(N_NODES+255)/256, b256, 0, stream>>>(deg, cnt, N_NODES);
  k_degree<<<(ET+255)/256, b256, 0, stream>>>(ei, deg, flag);
  k_scan_part<<<SCAN_NB, b256, 0, stream>>>(deg, loc, part);
  k_scan_carry<<<1, b256, 0, stream>>>(part, carry);
  k_scan_add<<<SCAN_NB, b256, 0, stream>>>(loc, carry, row_ptr);
  k_fill<<<(ET+255)/256, b256, 0, stream>>>(ei, row_ptr, cnt, col, flag);
  // merged weight prep (one launch)
  k_wprep<<<324, b256, 0, stream>>>(W1, W2, as2, ad2, Bp1, Bp, ws2, wd2);

  int nnode_blocks = (N_NODES + 3)/4;          // 4 waves = 4 nodes per block
  int nh_blocks = (N_NODES*8 + 255)/256;
  // layer 1
  k_gemm1_mfma<<<NPAD/64, b256, 0, stream>>>(x, Bp1, h1);
  k_alpha1<<<nh_blocks, b256, 0, stream>>>(h1, as1, ad1, als1, ald1);
  k_attn_agg1<<<nnode_blocks, b256, 0, stream>>>(h1, als1, ald1, row_ptr, col,
                                                 b1, hr);
  // layer 2
  k_alpha2<<<nh_blocks, b256, 0, stream>>>(hr, ws2, wd2, als2, ald2);
  k_attn_agg2<<<nnode_blocks, b256, 0, stream>>>(hr, als2, ald2, row_ptr, col, aggb);
  k_gemm_out_mfma<<<NPAD/64, b256, 0, stream>>>(aggb, Bp, b2, outp);
}

// Round 10
// 384.642 us; speedup vs baseline: 1.1392x; 1.1392x over previous
//
#include <hip/hip_runtime.h>

#define N_NODES 50000
#define N_EDGES 800000
#define ET (N_EDGES + N_NODES)   // 850000 incl. self loops
#define HEADS 8
#define NPAD 50048               // 782 blocks * 64 nodes
#define SCAN_NB 196              // ceil(50000/256)
#define CAP 96                   // LDS-cached edges per node (deg>CAP -> recompute)

typedef __attribute__((ext_vector_type(8))) _Float16 half8;
typedef __attribute__((ext_vector_type(2))) _Float16 half2v;
typedef __attribute__((ext_vector_type(4))) float f32x4;

__device__ __forceinline__ int edge_src(const int* ei, int e, int is64){
  if (e >= N_EDGES) return e - N_EDGES;          // self loop
  return is64 ? ei[2*e] : ei[e];
}
__device__ __forceinline__ int edge_dst(const int* ei, int e, int is64){
  if (e >= N_EDGES) return e - N_EDGES;          // self loop
  return is64 ? ei[2*(N_EDGES + e)] : ei[N_EDGES + e];
}

// ---------------- init: zero deg/cnt + edge-index layout detection ----------------
__global__ void k_init(const int* __restrict__ ei, int* __restrict__ deg,
                       int* __restrict__ cnt, int* __restrict__ flag){
  int i = blockIdx.x*blockDim.x + threadIdx.x;
  if (i < N_NODES){ deg[i] = 0; cnt[i] = 0; }
  if (i == 0){
    int zeros = 0;
    for (int k = 0; k < 64; k++){
      if (ei[2*k + 1] == 0) zeros++;
    }
    *flag = (zeros >= 60) ? 1 : 0;   // 1 => int64 little-endian layout
  }
}

__global__ void k_degree(const int* __restrict__ ei, int* __restrict__ deg,
                         const int* __restrict__ flag){
  int e = blockIdx.x*blockDim.x + threadIdx.x;
  if (e >= ET) return;
  int is64 = *flag;
  int d = edge_dst(ei, e, is64);
  atomicAdd(&deg[d], 1);
}

// ---- 3-stage scan ----
__global__ void k_scan_part(const int* __restrict__ deg, int* __restrict__ loc,
                            int* __restrict__ part){
  __shared__ int lds[256];
  int t = threadIdx.x, i = blockIdx.x*256 + t;
  int v = (i < N_NODES) ? deg[i] : 0;
  lds[t] = v;
  __syncthreads();
  for (int off = 1; off < 256; off <<= 1){
    int x = (t >= off) ? lds[t - off] : 0;
    __syncthreads();
    lds[t] += x;
    __syncthreads();
  }
  if (i < N_NODES) loc[i] = lds[t] - v;          // local exclusive
  if (t == 255) part[blockIdx.x] = lds[255];
}

__global__ void k_scan_carry(int* __restrict__ part, int* __restrict__ carry){
  __shared__ int lds[256];
  int t = threadIdx.x;
  int v = (t < SCAN_NB) ? part[t] : 0;
  lds[t] = v;
  __syncthreads();
  for (int off = 1; off < 256; off <<= 1){
    int x = (t >= off) ? lds[t - off] : 0;
    __syncthreads();
    lds[t] += x;
    __syncthreads();
  }
  if (t < SCAN_NB) carry[t] = lds[t] - v;        // exclusive over blocks
}

__global__ void k_scan_add(const int* __restrict__ loc, const int* __restrict__ carry,
                           int* __restrict__ row_ptr){
  int i = blockIdx.x*blockDim.x + threadIdx.x;
  if (i < N_NODES) row_ptr[i] = loc[i] + carry[i >> 8];
  if (i == 0) row_ptr[N_NODES] = ET;
}

__global__ void k_fill(const int* __restrict__ ei, const int* __restrict__ row_ptr,
                       int* __restrict__ cnt, int* __restrict__ col,
                       const int* __restrict__ flag){
  int e = blockIdx.x*blockDim.x + threadIdx.x;
  if (e >= ET) return;
  int is64 = *flag;
  int s = edge_src(ei, e, is64);
  int d = edge_dst(ei, e, is64);
  int pos = atomicAdd(&cnt[d], 1);
  col[row_ptr[d] + pos] = s;
}

// ---------------- merged weight prep (one launch) ----------------
// blocks [0,256): W2 pack; [256,320): W1 pack; [320,324): wtilde
__global__ void k_wprep(const float* __restrict__ W1, const float* __restrict__ W2,
                        const float* __restrict__ as2, const float* __restrict__ ad2,
                        _Float16* __restrict__ Bp1, _Float16* __restrict__ Bp,
                        float* __restrict__ ws2, float* __restrict__ wd2){
  int b = blockIdx.x;
  int t_ = threadIdx.x;
  if (b < 256){
    int t = b*256 + t_;
    int j = t & 7, lane = (t >> 3) & 63, nt = (t >> 9) & 3, kt = t >> 11;
    int k = kt*32 + (lane >> 4)*8 + j;
    int c = nt*16 + (lane & 15);
    int h = k >> 7, kk = k & 127;
    Bp[t] = (_Float16)(0.125f * W2[kk*512 + h*64 + c]);
  } else if (b < 320){
    int t = (b - 256)*256 + t_;
    int j = t & 7, lane = (t >> 3) & 63, nt = (t >> 9) & 7, kt = t >> 12;
    int k = kt*32 + (lane >> 4)*8 + j;
    int c = nt*16 + (lane & 15);
    Bp1[t] = (_Float16)W1[k*128 + c];
  } else {
    int t = (b - 320)*256 + t_;
    int k = t >> 3, h = t & 7;
    float s = 0.f, d = 0.f;
    for (int dd = 0; dd < 64; dd++){
      float w = W2[k*512 + h*64 + dd];
      s += w * as2[h*64 + dd];
      d += w * ad2[h*64 + dd];
    }
    ws2[h*128 + k] = s;
    wd2[h*128 + k] = d;
  }
}

// ---------------- layer 1 GEMM via MFMA: h1[N,128] = x @ W1 (fp16 out) ----------------
__global__ void __launch_bounds__(256) k_gemm1_mfma(
    const float* __restrict__ x, const _Float16* __restrict__ Bp1,
    _Float16* __restrict__ h1){
  int tid = threadIdx.x;
  int lane = tid & 63, wv = tid >> 6;
  int n0 = blockIdx.x*64 + wv*16;
  int rowA = n0 + (lane & 15);
  int koff = (lane >> 4)*8;
  const float* xr = x + (size_t)rowA*128 + koff;
  f32x4 acc[8];
  #pragma unroll
  for (int i = 0; i < 8; i++) acc[i] = (f32x4){0.f,0.f,0.f,0.f};
  bool inb = (rowA < N_NODES);
  #pragma unroll
  for (int kt = 0; kt < 4; kt++){
    half8 af;
    if (inb){
      float4 a0 = *(const float4*)(xr + kt*32);
      float4 a1 = *(const float4*)(xr + kt*32 + 4);
      af = (half8){(_Float16)a0.x,(_Float16)a0.y,(_Float16)a0.z,(_Float16)a0.w,
                   (_Float16)a1.x,(_Float16)a1.y,(_Float16)a1.z,(_Float16)a1.w};
    } else {
      af = (half8){0,0,0,0,0,0,0,0};
    }
    #pragma unroll
    for (int nt = 0; nt < 8; nt++){
      half8 bf = *(const half8*)(Bp1 + (((kt*8 + nt)*64 + lane) << 3));
      acc[nt] = __builtin_amdgcn_mfma_f32_16x16x32_f16(af, bf, acc[nt], 0, 0, 0);
    }
  }
  int r0 = n0 + (lane >> 4)*4;     // C/D: col=lane&15, row=(lane>>4)*4+reg  [m89]
  #pragma unroll
  for (int nt = 0; nt < 8; nt++){
    int c = nt*16 + (lane & 15);
    #pragma unroll
    for (int r = 0; r < 4; r++){
      int n = r0 + r;
      if (n < N_NODES) h1[(size_t)n*128 + c] = (_Float16)acc[nt][r];
    }
  }
}

// ---- alpha logits, layer 1 ----
__global__ void k_alpha1(const _Float16* __restrict__ h1, const float* __restrict__ as1,
                         const float* __restrict__ ad1,
                         float* __restrict__ als, float* __restrict__ ald){
  int t = blockIdx.x*blockDim.x + threadIdx.x;
  if (t >= N_NODES*8) return;
  int n = t >> 3, hh = t & 7;
  const half2v* hp = (const half2v*)(h1 + (size_t)n*128 + hh*16);
  float s = 0.f, d = 0.f;
  #pragma unroll
  for (int i = 0; i < 8; i++){
    half2v v = hp[i];
    float vx = (float)v.x, vy = (float)v.y;
    s += vx*as1[hh*16 + 2*i] + vy*as1[hh*16 + 2*i + 1];
    d += vx*ad1[hh*16 + 2*i] + vy*ad1[hh*16 + 2*i + 1];
  }
  als[t] = s; ald[t] = d;
}

// ===== layer 1: two-phase softmax+agg, LDS exp+col cache, fp32 acc =====
// phase 1: item-parallel leaky+exp -> LDS fp16 exp(a) + col ints; l = sum(exp)
// phase 2: lane owns channels {2L,2L+1}, head hh0=L>>3; w = es*inv (no exp!)
// epilogue: hr write + layer-2 alpha logits via butterflies (alpha2 fused)
__global__ void k_attn_agg1(const _Float16* __restrict__ h1,
    const float* __restrict__ als, const float* __restrict__ ald,
    const int* __restrict__ row_ptr, const int* __restrict__ col,
    const float* __restrict__ bias, _Float16* __restrict__ hr,
    const float* __restrict__ ws2, const float* __restrict__ wd2,
    float* __restrict__ als2, float* __restrict__ ald2){
  __shared__ _Float16 ew_s[4][CAP*8];
  __shared__ int col_s[4][CAP];
  int tid = threadIdx.x;
  int wv = tid >> 6, lane = tid & 63;
  int n = blockIdx.x*4 + wv;              // grid exact: 12500*4 = 50000
  int beg = row_ptr[n], end = row_ptr[n+1];
  int deg = end - beg;
  int items = deg*8;
  int h = lane & 7;
  float ad = ald[n*8 + h];
  _Float16* es = ew_s[wv];
  int* cs = col_s[wv];
  float l = 0.f;
  for (int it = lane; it < items; it += 64){
    int e = it >> 3;
    int s = col[beg + e];
    float a = als[s*8 + h] + ad;
    a = (a > 0.f) ? a : 0.2f*a;
    float ex = __expf(a);
    if (it < CAP*8){
      es[it] = (_Float16)ex;
      if ((it & 7) == 0) cs[e] = s;
    }
    l += ex;
  }
  l += __shfl_xor(l, 8, 64);
  l += __shfl_xor(l, 16, 64);
  l += __shfl_xor(l, 32, 64);
  float inv = 1.f / (l + 1e-16f);
  __syncthreads();
  int hh0 = lane >> 3;
  float invh = __shfl(inv, hh0, 64);
  const half2v* h2p = (const half2v*)h1;
  float ax = 0.f, ay = 0.f;
  int degc = deg < CAP ? deg : CAP;
  int j = 0;
  for (; j + 3 < degc; j += 4){
    int s0 = cs[j], s1 = cs[j+1], s2 = cs[j+2], s3 = cs[j+3];
    float w0 = (float)es[j*8 + hh0]     * invh;
    float w1 = (float)es[(j+1)*8 + hh0] * invh;
    float w2 = (float)es[(j+2)*8 + hh0] * invh;
    float w3 = (float)es[(j+3)*8 + hh0] * invh;
    half2v v0 = h2p[(size_t)s0*64 + lane];
    half2v v1 = h2p[(size_t)s1*64 + lane];
    half2v v2 = h2p[(size_t)s2*64 + lane];
    half2v v3 = h2p[(size_t)s3*64 + lane];
    ax += w0*(float)v0.x + w1*(float)v1.x + w2*(float)v2.x + w3*(float)v3.x;
    ay += w0*(float)v0.y + w1*(float)v1.y + w2*(float)v2.y + w3*(float)v3.y;
  }
  for (; j < degc; j++){
    int s = cs[j];
    float w = (float)es[j*8 + hh0] * invh;
    half2v v = h2p[(size_t)s*64 + lane];
    ax += w*(float)v.x; ay += w*(float)v.y;
  }
  float adh = ald[n*8 + hh0];
  for (; j < deg; j++){                       // rare: deg > CAP
    int s = col[beg + j];
    float a = als[s*8 + hh0] + adh;
    a = (a > 0.f) ? a : 0.2f*a;
    float w = __expf(a)*invh;
    half2v v = h2p[(size_t)s*64 + lane];
    ax += w*(float)v.x; ay += w*(float)v.y;
  }
  float2 bb = ((const float2*)bias)[lane];
  float o0 = fmaxf(ax + bb.x, 0.f);
  float o1 = fmaxf(ay + bb.y, 0.f);
  half2v oo; oo.x = (_Float16)o0; oo.y = (_Float16)o1;
  ((half2v*)hr)[(size_t)n*64 + lane] = oo;
  // fused alpha2: als2/ald2[n,h] = sum_k hr[n,k]*wtilde[h,k]
  const float2* wsp = (const float2*)ws2;
  const float2* wdp = (const float2*)wd2;
  #pragma unroll
  for (int hh = 0; hh < 8; hh++){
    float2 a = wsp[hh*64 + lane];
    float2 b = wdp[hh*64 + lane];
    float vs = o0*a.x + o1*a.y;
    float vd = o0*b.x + o1*b.y;
    #pragma unroll
    for (int off = 1; off < 64; off <<= 1){
      vs += __shfl_xor(vs, off, 64);
      vd += __shfl_xor(vd, off, 64);
    }
    if (lane == 0){
      als2[n*8 + hh] = vs;
      ald2[n*8 + hh] = vd;
    }
  }
}

// ===== layer 2: two-phase softmax+agg, LDS exp+col cache, fp16 pk acc =====
// phase 2 lane mapping: head hq=lane&7 (own softmax state), channels gq*16..+15;
// normalized fp16 weights (<=1) -> v_pk_fma_f16 accumulation.
__global__ void k_attn_agg2(const _Float16* __restrict__ hr,
    const float* __restrict__ als, const float* __restrict__ ald,
    const int* __restrict__ row_ptr, const int* __restrict__ col,
    _Float16* __restrict__ aggb){
  __shared__ _Float16 ew_s[4][CAP*8];
  __shared__ int col_s[4][CAP];
  int tid = threadIdx.x;
  int wv = tid >> 6, lane = tid & 63;
  int n = blockIdx.x*4 + wv;              // grid exact
  int beg = row_ptr[n], end = row_ptr[n+1];
  int deg = end - beg;
  int items = deg*8;
  int h = lane & 7;
  float ad = ald[n*8 + h];
  _Float16* es = ew_s[wv];
  int* cs = col_s[wv];
  float l = 0.f;
  for (int it = lane; it < items; it += 64){
    int e = it >> 3;
    int s = col[beg + e];
    float a = als[s*8 + h] + ad;
    a = (a > 0.f) ? a : 0.2f*a;
    float ex = __expf(a);
    if (it < CAP*8){
      es[it] = (_Float16)ex;
      if ((it & 7) == 0) cs[e] = s;
    }
    l += ex;
  }
  l += __shfl_xor(l, 8, 64);
  l += __shfl_xor(l, 16, 64);
  l += __shfl_xor(l, 32, 64);
  float inv = 1.f / (l + 1e-16f);   // for head hq = lane&7
  __syncthreads();
  int hq = lane & 7, gq = lane >> 3;
  _Float16 inv16 = (_Float16)inv;
  half2v acc[8];
  #pragma unroll
  for (int i = 0; i < 8; i++) acc[i] = (half2v){(_Float16)0.f, (_Float16)0.f};
  int degc = deg < CAP ? deg : CAP;
  int j = 0;
  for (; j + 3 < degc; j += 4){
    int s0 = cs[j], s1 = cs[j+1], s2 = cs[j+2], s3 = cs[j+3];
    _Float16 w0 = es[j*8 + hq]     * inv16;
    _Float16 w1 = es[(j+1)*8 + hq] * inv16;
    _Float16 w2 = es[(j+2)*8 + hq] * inv16;
    _Float16 w3 = es[(j+3)*8 + hq] * inv16;
    half2v w0p = {w0, w0}, w1p = {w1, w1}, w2p = {w2, w2}, w3p = {w3, w3};
    const _Float16* p0 = hr + (size_t)s0*128 + gq*16;
    const _Float16* p1 = hr + (size_t)s1*128 + gq*16;
    const _Float16* p2 = hr + (size_t)s2*128 + gq*16;
    const _Float16* p3 = hr + (size_t)s3*128 + gq*16;
    half8 va0 = *(const half8*)p0, vb0 = *(const half8*)(p0 + 8);
    half8 va1 = *(const half8*)p1, vb1 = *(const half8*)(p1 + 8);
    half8 va2 = *(const half8*)p2, vb2 = *(const half8*)(p2 + 8);
    half8 va3 = *(const half8*)p3, vb3 = *(const half8*)(p3 + 8);
    #pragma unroll
    for (int k = 0; k < 4; k++){
      acc[k]   += w0p * (half2v){va0[2*k], va0[2*k+1]};
      acc[k+4] += w0p * (half2v){vb0[2*k], vb0[2*k+1]};
      acc[k]   += w1p * (half2v){va1[2*k], va1[2*k+1]};
      acc[k+4] += w1p * (half2v){vb1[2*k], vb1[2*k+1]};
      acc[k]   += w2p * (half2v){va2[2*k], va2[2*k+1]};
      acc[k+4] += w2p * (half2v){vb2[2*k], vb2[2*k+1]};
      acc[k]   += w3p * (half2v){va3[2*k], va3[2*k+1]};
      acc[k+4] += w3p * (half2v){vb3[2*k], vb3[2*k+1]};
    }
  }
  for (; j < degc; j++){
    int s = cs[j];
    _Float16 wh = es[j*8 + hq] * inv16;
    half2v wp = {wh, wh};
    const _Float16* p = hr + (size_t)s*128 + gq*16;
    half8 va = *(const half8*)p, vb = *(const half8*)(p + 8);
    #pragma unroll
    for (int k = 0; k < 4; k++){
      acc[k]   += wp * (half2v){va[2*k], va[2*k+1]};
      acc[k+4] += wp * (half2v){vb[2*k], vb[2*k+1]};
    }
  }
  for (; j < deg; j++){                       // rare: deg > CAP
    int s = col[beg + j];
    float a = als[s*8 + hq] + ad;
    a = (a > 0.f) ? a : 0.2f*a;
    _Float16 wh = (_Float16)(__expf(a)*inv);
    half2v wp = {wh, wh};
    const _Float16* p = hr + (size_t)s*128 + gq*16;
    half8 va = *(const half8*)p, vb = *(const half8*)(p + 8);
    #pragma unroll
    for (int k = 0; k < 4; k++){
      acc[k]   += wp * (half2v){va[2*k], va[2*k+1]};
      acc[k+4] += wp * (half2v){vb[2*k], vb[2*k+1]};
    }
  }
  _Float16* ar = aggb + (size_t)n*1024 + hq*128 + gq*16;
  half8 oa, ob;
  #pragma unroll
  for (int k = 0; k < 4; k++){
    oa[2*k] = acc[k].x;   oa[2*k+1] = acc[k].y;
    ob[2*k] = acc[k+4].x; ob[2*k+1] = acc[k+4].y;
  }
  *(half8*)ar = oa;
  *(half8*)(ar + 8) = ob;
}

// ------- layer-2 output GEMM via MFMA f16: out = agg[N,1024] @ Wt[1024,64] + b2 -------
__global__ void __launch_bounds__(256) k_gemm_out_mfma(
    const _Float16* __restrict__ aggb, const _Float16* __restrict__ Bp,
    const float* __restrict__ b2, float* __restrict__ outp){
  int tid = threadIdx.x;
  int lane = tid & 63, wv = tid >> 6;
  int n0 = blockIdx.x*64 + wv*16;
  int rowA = n0 + (lane & 15);
  const _Float16* arow = aggb + (size_t)rowA*1024 + (lane >> 4)*8;
  f32x4 acc[4];
  #pragma unroll
  for (int i = 0; i < 4; i++) acc[i] = (f32x4){0.f,0.f,0.f,0.f};
  half8 af = *(const half8*)(arow);
  for (int kt = 0; kt < 32; kt++){
    half8 afn;
    if (kt + 1 < 32) afn = *(const half8*)(arow + (kt+1)*32);
    #pragma unroll
    for (int nt = 0; nt < 4; nt++){
      half8 bf = *(const half8*)(Bp + (((kt*4 + nt)*64 + lane) << 3));
      acc[nt] = __builtin_amdgcn_mfma_f32_16x16x32_f16(af, bf, acc[nt], 0, 0, 0);
    }
    af = afn;
  }
  int r0 = n0 + (lane >> 4)*4;     // C/D: col=lane&15, row=(lane>>4)*4+reg  [m89]
  #pragma unroll
  for (int nt = 0; nt < 4; nt++){
    int c = nt*16 + (lane & 15);
    float bb = b2[c];
    #pragma unroll
    for (int r = 0; r < 4; r++){
      int n = r0 + r;
      if (n < N_NODES) outp[n*64 + c] = acc[nt][r] + bb;
    }
  }
}

extern "C" void kernel_launch(void* const* d_in, const int* in_sizes, int n_in,
                              void* d_out, int out_size, void* d_ws, size_t ws_size,
                              hipStream_t stream){
  const float* x   = (const float*)d_in[0];
  const int*   ei  = (const int*)d_in[1];
  const float* W1  = (const float*)d_in[2];
  const float* as1 = (const float*)d_in[3];
  const float* ad1 = (const float*)d_in[4];
  const float* b1  = (const float*)d_in[5];
  const float* W2  = (const float*)d_in[6];
  const float* as2 = (const float*)d_in[7];
  const float* ad2 = (const float*)d_in[8];
  const float* b2  = (const float*)d_in[9];
  float* outp = (float*)d_out;

  char* p = (char*)d_ws;
  auto alloc = [&](size_t bytes) -> void* {
    void* r = (void*)p;
    p += (bytes + 255) & ~(size_t)255;
    return r;
  };
  // aggb (102.5 MB) also hosts h1 (12.8 MB) — h1 dead before k_attn_agg2 writes.
  _Float16* aggb = (_Float16*)alloc((size_t)NPAD*1024*2);
  _Float16* h1  = aggb;                                          // [N,128] fp16
  _Float16* hr  = (_Float16*)alloc((size_t)N_NODES*128*2);       // [N,128] fp16
  float* als1 = (float*)alloc((size_t)N_NODES*8*4);
  float* ald1 = (float*)alloc((size_t)N_NODES*8*4);
  float* als2 = (float*)alloc((size_t)N_NODES*8*4);
  float* ald2 = (float*)alloc((size_t)N_NODES*8*4);
  int* row_ptr = (int*)alloc((size_t)(N_NODES+1)*4);
  int* deg  = (int*)alloc((size_t)N_NODES*4);
  int* cnt  = (int*)alloc((size_t)N_NODES*4);
  int* col  = (int*)alloc((size_t)ET*4);
  int* loc  = (int*)alloc((size_t)N_NODES*4);
  int* part = (int*)alloc(256*4);
  int* carry= (int*)alloc(256*4);
  int* flag = (int*)alloc(256);
  float* ws2 = (float*)alloc(1024*4);
  float* wd2 = (float*)alloc(1024*4);
  _Float16* Bp1 = (_Float16*)alloc((size_t)16384*2);
  _Float16* Bp  = (_Float16*)alloc((size_t)65536*2);

  dim3 b256(256);
  // CSR build (init incl. layout probe)
  k_init<<<(N_NODES+255)/256, b256, 0, stream>>>(ei, deg, cnt, flag);
  k_degree<<<(ET+255)/256, b256, 0, stream>>>(ei, deg, flag);
  k_scan_part<<<SCAN_NB, b256, 0, stream>>>(deg, loc, part);
  k_scan_carry<<<1, b256, 0, stream>>>(part, carry);
  k_scan_add<<<SCAN_NB, b256, 0, stream>>>(loc, carry, row_ptr);
  k_fill<<<(ET+255)/256, b256, 0, stream>>>(ei, row_ptr, cnt, col, flag);
  // merged weight prep
  k_wprep<<<324, b256, 0, stream>>>(W1, W2, as2, ad2, Bp1, Bp, ws2, wd2);

  int nnode_blocks = N_NODES/4;                // 4 waves = 4 nodes per block, exact
  int nh_blocks = (N_NODES*8 + 255)/256;
  // layer 1
  k_gemm1_mfma<<<NPAD/64, b256, 0, stream>>>(x, Bp1, h1);
  k_alpha1<<<nh_blocks, b256, 0, stream>>>(h1, as1, ad1, als1, ald1);
  k_attn_agg1<<<nnode_blocks, b256, 0, stream>>>(h1, als1, ald1, row_ptr, col,
                                                 b1, hr, ws2, wd2, als2, ald2);
  // layer 2
  k_attn_agg2<<<nnode_blocks, b256, 0, stream>>>(hr, als2, ald2, row_ptr, col, aggb);
  k_gemm_out_mfma<<<NPAD/64, b256, 0, stream>>>(aggb, Bp, b2, outp);
}

// Round 11
// 374.963 us; speedup vs baseline: 1.1686x; 1.0258x over previous
//
#include <hip/hip_runtime.h>

#define N_NODES 50000
#define N_EDGES 800000
#define ET (N_EDGES + N_NODES)   // 850000 incl. self loops
#define HEADS 8
#define NPAD 50048               // 782 blocks * 64 nodes
#define SCAN_NB 196              // ceil(50000/256)
#define CAP 96                   // LDS-cached edges per node (deg>CAP -> recompute)

typedef __attribute__((ext_vector_type(8))) _Float16 half8;
typedef __attribute__((ext_vector_type(2))) _Float16 half2v;
typedef __attribute__((ext_vector_type(4))) float f32x4;

__device__ __forceinline__ int edge_src(const int* ei, int e, int is64){
  if (e >= N_EDGES) return e - N_EDGES;          // self loop
  return is64 ? ei[2*e] : ei[e];
}
__device__ __forceinline__ int edge_dst(const int* ei, int e, int is64){
  if (e >= N_EDGES) return e - N_EDGES;          // self loop
  return is64 ? ei[2*(N_EDGES + e)] : ei[N_EDGES + e];
}

// ---------------- init: zero deg/cnt + edge-index layout detection ----------------
__global__ void k_init(const int* __restrict__ ei, int* __restrict__ deg,
                       int* __restrict__ cnt, int* __restrict__ flag){
  int i = blockIdx.x*blockDim.x + threadIdx.x;
  if (i < N_NODES){ deg[i] = 0; cnt[i] = 0; }
  if (i == 0){
    int zeros = 0;
    for (int k = 0; k < 64; k++){
      if (ei[2*k + 1] == 0) zeros++;
    }
    *flag = (zeros >= 60) ? 1 : 0;   // 1 => int64 little-endian layout
  }
}

__global__ void k_degree(const int* __restrict__ ei, int* __restrict__ deg,
                         const int* __restrict__ flag){
  int e = blockIdx.x*blockDim.x + threadIdx.x;
  if (e >= ET) return;
  int is64 = *flag;
  int d = edge_dst(ei, e, is64);
  atomicAdd(&deg[d], 1);
}

// ---- 3-stage scan ----
__global__ void k_scan_part(const int* __restrict__ deg, int* __restrict__ loc,
                            int* __restrict__ part){
  __shared__ int lds[256];
  int t = threadIdx.x, i = blockIdx.x*256 + t;
  int v = (i < N_NODES) ? deg[i] : 0;
  lds[t] = v;
  __syncthreads();
  for (int off = 1; off < 256; off <<= 1){
    int x = (t >= off) ? lds[t - off] : 0;
    __syncthreads();
    lds[t] += x;
    __syncthreads();
  }
  if (i < N_NODES) loc[i] = lds[t] - v;          // local exclusive
  if (t == 255) part[blockIdx.x] = lds[255];
}

__global__ void k_scan_carry(int* __restrict__ part, int* __restrict__ carry){
  __shared__ int lds[256];
  int t = threadIdx.x;
  int v = (t < SCAN_NB) ? part[t] : 0;
  lds[t] = v;
  __syncthreads();
  for (int off = 1; off < 256; off <<= 1){
    int x = (t >= off) ? lds[t - off] : 0;
    __syncthreads();
    lds[t] += x;
    __syncthreads();
  }
  if (t < SCAN_NB) carry[t] = lds[t] - v;        // exclusive over blocks
}

__global__ void k_scan_add(const int* __restrict__ loc, const int* __restrict__ carry,
                           int* __restrict__ row_ptr){
  int i = blockIdx.x*blockDim.x + threadIdx.x;
  if (i < N_NODES) row_ptr[i] = loc[i] + carry[i >> 8];
  if (i == 0) row_ptr[N_NODES] = ET;
}

__global__ void k_fill(const int* __restrict__ ei, const int* __restrict__ row_ptr,
                       int* __restrict__ cnt, int* __restrict__ col,
                       const int* __restrict__ flag){
  int e = blockIdx.x*blockDim.x + threadIdx.x;
  if (e >= ET) return;
  int is64 = *flag;
  int s = edge_src(ei, e, is64);
  int d = edge_dst(ei, e, is64);
  int pos = atomicAdd(&cnt[d], 1);
  col[row_ptr[d] + pos] = s;
}

// ---------------- merged weight prep (one launch) ----------------
// blocks [0,256): W2 pack; [256,320): W1 pack; [320,324): wtilde
__global__ void k_wprep(const float* __restrict__ W1, const float* __restrict__ W2,
                        const float* __restrict__ as2, const float* __restrict__ ad2,
                        _Float16* __restrict__ Bp1, _Float16* __restrict__ Bp,
                        float* __restrict__ ws2, float* __restrict__ wd2){
  int b = blockIdx.x;
  int t_ = threadIdx.x;
  if (b < 256){
    int t = b*256 + t_;
    int j = t & 7, lane = (t >> 3) & 63, nt = (t >> 9) & 3, kt = t >> 11;
    int k = kt*32 + (lane >> 4)*8 + j;
    int c = nt*16 + (lane & 15);
    int h = k >> 7, kk = k & 127;
    Bp[t] = (_Float16)(0.125f * W2[kk*512 + h*64 + c]);
  } else if (b < 320){
    int t = (b - 256)*256 + t_;
    int j = t & 7, lane = (t >> 3) & 63, nt = (t >> 9) & 7, kt = t >> 12;
    int k = kt*32 + (lane >> 4)*8 + j;
    int c = nt*16 + (lane & 15);
    Bp1[t] = (_Float16)W1[k*128 + c];
  } else {
    int t = (b - 320)*256 + t_;
    int k = t >> 3, h = t & 7;
    float s = 0.f, d = 0.f;
    for (int dd = 0; dd < 64; dd++){
      float w = W2[k*512 + h*64 + dd];
      s += w * as2[h*64 + dd];
      d += w * ad2[h*64 + dd];
    }
    ws2[h*128 + k] = s;
    wd2[h*128 + k] = d;
  }
}

// ------ layer 1 GEMM via MFMA: h1 = x @ W1 (fp16 out) + fused alpha1 logits ------
__global__ void __launch_bounds__(256) k_gemm1_mfma(
    const float* __restrict__ x, const _Float16* __restrict__ Bp1,
    _Float16* __restrict__ h1,
    const float* __restrict__ as1, const float* __restrict__ ad1,
    float* __restrict__ als1, float* __restrict__ ald1){
  int tid = threadIdx.x;
  int lane = tid & 63, wv = tid >> 6;
  int n0 = blockIdx.x*64 + wv*16;
  int rowA = n0 + (lane & 15);
  int koff = (lane >> 4)*8;
  const float* xr = x + (size_t)rowA*128 + koff;
  f32x4 acc[8];
  #pragma unroll
  for (int i = 0; i < 8; i++) acc[i] = (f32x4){0.f,0.f,0.f,0.f};
  bool inb = (rowA < N_NODES);
  #pragma unroll
  for (int kt = 0; kt < 4; kt++){
    half8 af;
    if (inb){
      float4 a0 = *(const float4*)(xr + kt*32);
      float4 a1 = *(const float4*)(xr + kt*32 + 4);
      af = (half8){(_Float16)a0.x,(_Float16)a0.y,(_Float16)a0.z,(_Float16)a0.w,
                   (_Float16)a1.x,(_Float16)a1.y,(_Float16)a1.z,(_Float16)a1.w};
    } else {
      af = (half8){0,0,0,0,0,0,0,0};
    }
    #pragma unroll
    for (int nt = 0; nt < 8; nt++){
      half8 bf = *(const half8*)(Bp1 + (((kt*8 + nt)*64 + lane) << 3));
      acc[nt] = __builtin_amdgcn_mfma_f32_16x16x32_f16(af, bf, acc[nt], 0, 0, 0);
    }
  }
  int m = lane & 15, q = lane >> 4;
  int r0 = n0 + q*4;               // C/D: col=lane&15, row=(lane>>4)*4+reg  [m89]
  #pragma unroll
  for (int nt = 0; nt < 8; nt++){
    int c = nt*16 + m;
    #pragma unroll
    for (int r = 0; r < 4; r++){
      int n = r0 + r;
      if (n < N_NODES) h1[(size_t)n*128 + c] = (_Float16)acc[nt][r];
    }
  }
  // fused alpha1: lane's acc[nt][r] is channel (nt*16+m) == head nt, pos m of row r0+r
  float as1v[8], ad1v[8];
  #pragma unroll
  for (int nt = 0; nt < 8; nt++){
    as1v[nt] = as1[nt*16 + m];
    ad1v[nt] = ad1[nt*16 + m];
  }
  #pragma unroll
  for (int r = 0; r < 4; r++){
    float vs[8], vd[8];
    #pragma unroll
    for (int nt = 0; nt < 8; nt++){
      vs[nt] = acc[nt][r]*as1v[nt];
      vd[nt] = acc[nt][r]*ad1v[nt];
      #pragma unroll
      for (int off = 1; off < 16; off <<= 1){
        vs[nt] += __shfl_xor(vs[nt], off, 64);
        vd[nt] += __shfl_xor(vd[nt], off, 64);
      }
    }
    int n = r0 + r;
    if (m == r && n < N_NODES){
      float4 v0; v0.x = vs[0]; v0.y = vs[1]; v0.z = vs[2]; v0.w = vs[3];
      float4 v1; v1.x = vs[4]; v1.y = vs[5]; v1.z = vs[6]; v1.w = vs[7];
      float4 w0; w0.x = vd[0]; w0.y = vd[1]; w0.z = vd[2]; w0.w = vd[3];
      float4 w1; w1.x = vd[4]; w1.y = vd[5]; w1.z = vd[6]; w1.w = vd[7];
      *(float4*)&als1[n*8]     = v0;
      *(float4*)&als1[n*8 + 4] = v1;
      *(float4*)&ald1[n*8]     = w0;
      *(float4*)&ald1[n*8 + 4] = w1;
    }
  }
}

// ===== layer 1: two-phase softmax+agg, LDS exp+col cache, fp32 acc =====
// phase 1: item-parallel leaky+exp -> LDS fp16 exp(a) + col ints; l = sum(exp)
// phase 2: lane owns channels {2L,2L+1}, head hh0=L>>3; w = es*inv; unroll 8
// epilogue: hr write + alpha2 logits via LDS transpose (one head-segment per lane)
__global__ void k_attn_agg1(const _Float16* __restrict__ h1,
    const float* __restrict__ als, const float* __restrict__ ald,
    const int* __restrict__ row_ptr, const int* __restrict__ col,
    const float* __restrict__ bias, _Float16* __restrict__ hr,
    const float* __restrict__ ws2, const float* __restrict__ wd2,
    float* __restrict__ als2, float* __restrict__ ald2){
  __shared__ _Float16 ew_s[4][CAP*8];
  __shared__ int col_s[4][CAP];
  __shared__ _Float16 ot_s[4][132];
  int tid = threadIdx.x;
  int wv = tid >> 6, lane = tid & 63;
  int n = blockIdx.x*4 + wv;              // grid exact: 12500*4 = 50000
  int beg = row_ptr[n], end = row_ptr[n+1];
  int deg = end - beg;
  int items = deg*8;
  int h = lane & 7;
  float ad = ald[n*8 + h];
  _Float16* es = ew_s[wv];
  int* cs = col_s[wv];
  float l = 0.f;
  int itc = items < CAP*8 ? items : CAP*8;
  int it = lane;
  for (; it < itc; it += 64){             // cached range: store es + col
    int e = it >> 3;
    int s = col[beg + e];
    float a = als[s*8 + h] + ad;
    a = (a > 0.f) ? a : 0.2f*a;
    float ex = __expf(a);
    es[it] = (_Float16)ex;
    if ((it & 7) == 0) cs[e] = s;
    l += ex;
  }
  for (; it < items; it += 64){           // rare overflow range
    int s = col[beg + (it >> 3)];
    float a = als[s*8 + h] + ad;
    a = (a > 0.f) ? a : 0.2f*a;
    l += __expf(a);
  }
  l += __shfl_xor(l, 8, 64);
  l += __shfl_xor(l, 16, 64);
  l += __shfl_xor(l, 32, 64);
  float inv = 1.f / (l + 1e-16f);
  __syncthreads();
  int hh0 = lane >> 3;
  float invh = __shfl(inv, hh0, 64);
  const half2v* h2p = (const half2v*)h1;
  float ax = 0.f, ay = 0.f;
  int degc = deg < CAP ? deg : CAP;
  int j = 0;
  for (; j + 7 < degc; j += 8){
    int s[8]; float w[8]; half2v v[8];
    #pragma unroll
    for (int u = 0; u < 8; u++) s[u] = cs[j + u];
    #pragma unroll
    for (int u = 0; u < 8; u++) w[u] = (float)es[(j + u)*8 + hh0] * invh;
    #pragma unroll
    for (int u = 0; u < 8; u++) v[u] = h2p[(size_t)s[u]*64 + lane];
    #pragma unroll
    for (int u = 0; u < 8; u++){ ax += w[u]*(float)v[u].x; ay += w[u]*(float)v[u].y; }
  }
  for (; j < degc; j++){
    int s = cs[j];
    float w = (float)es[j*8 + hh0] * invh;
    half2v v = h2p[(size_t)s*64 + lane];
    ax += w*(float)v.x; ay += w*(float)v.y;
  }
  float adh = ald[n*8 + hh0];
  for (; j < deg; j++){                       // rare: deg > CAP
    int s = col[beg + j];
    float a = als[s*8 + hh0] + adh;
    a = (a > 0.f) ? a : 0.2f*a;
    float w = __expf(a)*invh;
    half2v v = h2p[(size_t)s*64 + lane];
    ax += w*(float)v.x; ay += w*(float)v.y;
  }
  float2 bb = ((const float2*)bias)[lane];
  float o0 = fmaxf(ax + bb.x, 0.f);
  float o1 = fmaxf(ay + bb.y, 0.f);
  half2v oo; oo.x = (_Float16)o0; oo.y = (_Float16)o1;
  ((half2v*)hr)[(size_t)n*64 + lane] = oo;
  // fused alpha2 via LDS transpose: lane -> (head hh=lane>>3, segment seg=lane&7)
  ((half2v*)&ot_s[wv][0])[lane] = oo;     // same-wave LDS, no barrier needed
  int hh = lane >> 3, seg = lane & 7;
  const half2v* otp = (const half2v*)&ot_s[wv][0];
  const float* wsr = ws2 + hh*128 + seg*16;
  const float* wdr = wd2 + hh*128 + seg*16;
  float vs = 0.f, vd = 0.f;
  #pragma unroll
  for (int i = 0; i < 8; i++){
    half2v v = otp[seg*8 + i];
    float vx = (float)v.x, vy = (float)v.y;
    vs += vx*wsr[2*i] + vy*wsr[2*i + 1];
    vd += vx*wdr[2*i] + vy*wdr[2*i + 1];
  }
  vs += __shfl_xor(vs, 1, 64); vd += __shfl_xor(vd, 1, 64);
  vs += __shfl_xor(vs, 2, 64); vd += __shfl_xor(vd, 2, 64);
  vs += __shfl_xor(vs, 4, 64); vd += __shfl_xor(vd, 4, 64);
  if (seg == 0){
    als2[n*8 + hh] = vs;
    ald2[n*8 + hh] = vd;
  }
}

// ===== layer 2: two-phase softmax+agg, LDS exp+col cache, fp16 pk acc =====
__global__ void k_attn_agg2(const _Float16* __restrict__ hr,
    const float* __restrict__ als, const float* __restrict__ ald,
    const int* __restrict__ row_ptr, const int* __restrict__ col,
    _Float16* __restrict__ aggb){
  __shared__ _Float16 ew_s[4][CAP*8];
  __shared__ int col_s[4][CAP];
  int tid = threadIdx.x;
  int wv = tid >> 6, lane = tid & 63;
  int n = blockIdx.x*4 + wv;              // grid exact
  int beg = row_ptr[n], end = row_ptr[n+1];
  int deg = end - beg;
  int items = deg*8;
  int h = lane & 7;
  float ad = ald[n*8 + h];
  _Float16* es = ew_s[wv];
  int* cs = col_s[wv];
  float l = 0.f;
  int itc = items < CAP*8 ? items : CAP*8;
  int it = lane;
  for (; it < itc; it += 64){
    int e = it >> 3;
    int s = col[beg + e];
    float a = als[s*8 + h] + ad;
    a = (a > 0.f) ? a : 0.2f*a;
    float ex = __expf(a);
    es[it] = (_Float16)ex;
    if ((it & 7) == 0) cs[e] = s;
    l += ex;
  }
  for (; it < items; it += 64){
    int s = col[beg + (it >> 3)];
    float a = als[s*8 + h] + ad;
    a = (a > 0.f) ? a : 0.2f*a;
    l += __expf(a);
  }
  l += __shfl_xor(l, 8, 64);
  l += __shfl_xor(l, 16, 64);
  l += __shfl_xor(l, 32, 64);
  float inv = 1.f / (l + 1e-16f);   // for head hq = lane&7
  __syncthreads();
  int hq = lane & 7, gq = lane >> 3;
  _Float16 inv16 = (_Float16)inv;
  half2v acc[8];
  #pragma unroll
  for (int i = 0; i < 8; i++) acc[i] = (half2v){(_Float16)0.f, (_Float16)0.f};
  int degc = deg < CAP ? deg : CAP;
  int j = 0;
  for (; j + 3 < degc; j += 4){
    int s0 = cs[j], s1 = cs[j+1], s2 = cs[j+2], s3 = cs[j+3];
    _Float16 w0 = es[j*8 + hq]     * inv16;
    _Float16 w1 = es[(j+1)*8 + hq] * inv16;
    _Float16 w2 = es[(j+2)*8 + hq] * inv16;
    _Float16 w3 = es[(j+3)*8 + hq] * inv16;
    half2v w0p = {w0, w0}, w1p = {w1, w1}, w2p = {w2, w2}, w3p = {w3, w3};
    const _Float16* p0 = hr + (size_t)s0*128 + gq*16;
    const _Float16* p1 = hr + (size_t)s1*128 + gq*16;
    const _Float16* p2 = hr + (size_t)s2*128 + gq*16;
    const _Float16* p3 = hr + (size_t)s3*128 + gq*16;
    half8 va0 = *(const half8*)p0, vb0 = *(const half8*)(p0 + 8);
    half8 va1 = *(const half8*)p1, vb1 = *(const half8*)(p1 + 8);
    half8 va2 = *(const half8*)p2, vb2 = *(const half8*)(p2 + 8);
    half8 va3 = *(const half8*)p3, vb3 = *(const half8*)(p3 + 8);
    #pragma unroll
    for (int k = 0; k < 4; k++){
      acc[k]   += w0p * (half2v){va0[2*k], va0[2*k+1]};
      acc[k+4] += w0p * (half2v){vb0[2*k], vb0[2*k+1]};
      acc[k]   += w1p * (half2v){va1[2*k], va1[2*k+1]};
      acc[k+4] += w1p * (half2v){vb1[2*k], vb1[2*k+1]};
      acc[k]   += w2p * (half2v){va2[2*k], va2[2*k+1]};
      acc[k+4] += w2p * (half2v){vb2[2*k], vb2[2*k+1]};
      acc[k]   += w3p * (half2v){va3[2*k], va3[2*k+1]};
      acc[k+4] += w3p * (half2v){vb3[2*k], vb3[2*k+1]};
    }
  }
  for (; j < degc; j++){
    int s = cs[j];
    _Float16 wh = es[j*8 + hq] * inv16;
    half2v wp = {wh, wh};
    const _Float16* p = hr + (size_t)s*128 + gq*16;
    half8 va = *(const half8*)p, vb = *(const half8*)(p + 8);
    #pragma unroll
    for (int k = 0; k < 4; k++){
      acc[k]   += wp * (half2v){va[2*k], va[2*k+1]};
      acc[k+4] += wp * (half2v){vb[2*k], vb[2*k+1]};
    }
  }
  for (; j < deg; j++){                       // rare: deg > CAP
    int s = col[beg + j];
    float a = als[s*8 + hq] + ad;
    a = (a > 0.f) ? a : 0.2f*a;
    _Float16 wh = (_Float16)(__expf(a)*inv);
    half2v wp = {wh, wh};
    const _Float16* p = hr + (size_t)s*128 + gq*16;
    half8 va = *(const half8*)p, vb = *(const half8*)(p + 8);
    #pragma unroll
    for (int k = 0; k < 4; k++){
      acc[k]   += wp * (half2v){va[2*k], va[2*k+1]};
      acc[k+4] += wp * (half2v){vb[2*k], vb[2*k+1]};
    }
  }
  _Float16* ar = aggb + (size_t)n*1024 + hq*128 + gq*16;
  half8 oa, ob;
  #pragma unroll
  for (int k = 0; k < 4; k++){
    oa[2*k] = acc[k].x;   oa[2*k+1] = acc[k].y;
    ob[2*k] = acc[k+4].x; ob[2*k+1] = acc[k+4].y;
  }
  *(half8*)ar = oa;
  *(half8*)(ar + 8) = ob;
}

// ------- layer-2 output GEMM via MFMA f16: out = agg[N,1024] @ Wt[1024,64] + b2 -------
__global__ void __launch_bounds__(256) k_gemm_out_mfma(
    const _Float16* __restrict__ aggb, const _Float16* __restrict__ Bp,
    const float* __restrict__ b2, float* __restrict__ outp){
  int tid = threadIdx.x;
  int lane = tid & 63, wv = tid >> 6;
  int n0 = blockIdx.x*64 + wv*16;
  int rowA = n0 + (lane & 15);
  const _Float16* arow = aggb + (size_t)rowA*1024 + (lane >> 4)*8;
  f32x4 acc[4];
  #pragma unroll
  for (int i = 0; i < 4; i++) acc[i] = (f32x4){0.f,0.f,0.f,0.f};
  half8 af = *(const half8*)(arow);
  for (int kt = 0; kt < 32; kt++){
    half8 afn;
    if (kt + 1 < 32) afn = *(const half8*)(arow + (kt+1)*32);
    #pragma unroll
    for (int nt = 0; nt < 4; nt++){
      half8 bf = *(const half8*)(Bp + (((kt*4 + nt)*64 + lane) << 3));
      acc[nt] = __builtin_amdgcn_mfma_f32_16x16x32_f16(af, bf, acc[nt], 0, 0, 0);
    }
    af = afn;
  }
  int r0 = n0 + (lane >> 4)*4;     // C/D: col=lane&15, row=(lane>>4)*4+reg  [m89]
  #pragma unroll
  for (int nt = 0; nt < 4; nt++){
    int c = nt*16 + (lane & 15);
    float bb = b2[c];
    #pragma unroll
    for (int r = 0; r < 4; r++){
      int n = r0 + r;
      if (n < N_NODES) outp[n*64 + c] = acc[nt][r] + bb;
    }
  }
}

extern "C" void kernel_launch(void* const* d_in, const int* in_sizes, int n_in,
                              void* d_out, int out_size, void* d_ws, size_t ws_size,
                              hipStream_t stream){
  const float* x   = (const float*)d_in[0];
  const int*   ei  = (const int*)d_in[1];
  const float* W1  = (const float*)d_in[2];
  const float* as1 = (const float*)d_in[3];
  const float* ad1 = (const float*)d_in[4];
  const float* b1  = (const float*)d_in[5];
  const float* W2  = (const float*)d_in[6];
  const float* as2 = (const float*)d_in[7];
  const float* ad2 = (const float*)d_in[8];
  const float* b2  = (const float*)d_in[9];
  float* outp = (float*)d_out;

  char* p = (char*)d_ws;
  auto alloc = [&](size_t bytes) -> void* {
    void* r = (void*)p;
    p += (bytes + 255) & ~(size_t)255;
    return r;
  };
  // aggb (102.5 MB) also hosts h1 (12.8 MB) — h1 dead before k_attn_agg2 writes.
  _Float16* aggb = (_Float16*)alloc((size_t)NPAD*1024*2);
  _Float16* h1  = aggb;                                          // [N,128] fp16
  _Float16* hr  = (_Float16*)alloc((size_t)N_NODES*128*2);       // [N,128] fp16
  float* als1 = (float*)alloc((size_t)N_NODES*8*4);
  float* ald1 = (float*)alloc((size_t)N_NODES*8*4);
  float* als2 = (float*)alloc((size_t)N_NODES*8*4);
  float* ald2 = (float*)alloc((size_t)N_NODES*8*4);
  int* row_ptr = (int*)alloc((size_t)(N_NODES+1)*4);
  int* deg  = (int*)alloc((size_t)N_NODES*4);
  int* cnt  = (int*)alloc((size_t)N_NODES*4);
  int* col  = (int*)alloc((size_t)ET*4);
  int* loc  = (int*)alloc((size_t)N_NODES*4);
  int* part = (int*)alloc(256*4);
  int* carry= (int*)alloc(256*4);
  int* flag = (int*)alloc(256);
  float* ws2 = (float*)alloc(1024*4);
  float* wd2 = (float*)alloc(1024*4);
  _Float16* Bp1 = (_Float16*)alloc((size_t)16384*2);
  _Float16* Bp  = (_Float16*)alloc((size_t)65536*2);

  dim3 b256(256);
  // CSR build (init incl. layout probe)
  k_init<<<(N_NODES+255)/256, b256, 0, stream>>>(ei, deg, cnt, flag);
  k_degree<<<(ET+255)/256, b256, 0, stream>>>(ei, deg, flag);
  k_scan_part<<<SCAN_NB, b256, 0, stream>>>(deg, loc, part);
  k_scan_carry<<<1, b256, 0, stream>>>(part, carry);
  k_scan_add<<<SCAN_NB, b256, 0, stream>>>(loc, carry, row_ptr);
  k_fill<<<(ET+255)/256, b256, 0, stream>>>(ei, row_ptr, cnt, col, flag);
  // merged weight prep
  k_wprep<<<324, b256, 0, stream>>>(W1, W2, as2, ad2, Bp1, Bp, ws2, wd2);

  int nnode_blocks = N_NODES/4;                // 4 waves = 4 nodes per block, exact
  // layer 1 (alpha1 fused into the GEMM epilogue)
  k_gemm1_mfma<<<NPAD/64, b256, 0, stream>>>(x, Bp1, h1, as1, ad1, als1, ald1);
  k_attn_agg1<<<nnode_blocks, b256, 0, stream>>>(h1, als1, ald1, row_ptr, col,
                                                 b1, hr, ws2, wd2, als2, ald2);
  // layer 2
  k_attn_agg2<<<nnode_blocks, b256, 0, stream>>>(hr, als2, ald2, row_ptr, col, aggb);
  k_gemm_out_mfma<<<NPAD/64, b256, 0, stream>>>(aggb, Bp, b2, outp);
}

// Round 12
// 354.845 us; speedup vs baseline: 1.2349x; 1.0567x over previous
//
#include <hip/hip_runtime.h>

#define N_NODES 50000
#define N_EDGES 800000
#define ET (N_EDGES + N_NODES)   // 850000 incl. self loops
#define HEADS 8
#define NPAD 50048               // 782 blocks * 64 nodes
#define SCAN_NB 196              // ceil(50000/256)
#define CAP 96                   // LDS-cached edges per node (deg>CAP -> recompute)
#define LRS 1032                 // LDS A-tile row stride (halves, 16B-aligned)

typedef __attribute__((ext_vector_type(8))) _Float16 half8;
typedef __attribute__((ext_vector_type(2))) _Float16 half2v;
typedef __attribute__((ext_vector_type(4))) float f32x4;

__device__ __forceinline__ int edge_src(const int* ei, int e, int is64){
  if (e >= N_EDGES) return e - N_EDGES;          // self loop
  return is64 ? ei[2*e] : ei[e];
}
__device__ __forceinline__ int edge_dst(const int* ei, int e, int is64){
  if (e >= N_EDGES) return e - N_EDGES;          // self loop
  return is64 ? ei[2*(N_EDGES + e)] : ei[N_EDGES + e];
}

// ---------------- init: zero deg/cnt + edge-index layout detection ----------------
__global__ void k_init(const int* __restrict__ ei, int* __restrict__ deg,
                       int* __restrict__ cnt, int* __restrict__ flag){
  int i = blockIdx.x*blockDim.x + threadIdx.x;
  if (i < N_NODES){ deg[i] = 0; cnt[i] = 0; }
  if (i == 0){
    int zeros = 0;
    for (int k = 0; k < 64; k++){
      if (ei[2*k + 1] == 0) zeros++;
    }
    *flag = (zeros >= 60) ? 1 : 0;   // 1 => int64 little-endian layout
  }
}

__global__ void k_degree(const int* __restrict__ ei, int* __restrict__ deg,
                         const int* __restrict__ flag){
  int e = blockIdx.x*blockDim.x + threadIdx.x;
  if (e >= ET) return;
  int is64 = *flag;
  int d = edge_dst(ei, e, is64);
  atomicAdd(&deg[d], 1);
}

// ---- 3-stage scan ----
__global__ void k_scan_part(const int* __restrict__ deg, int* __restrict__ loc,
                            int* __restrict__ part){
  __shared__ int lds[256];
  int t = threadIdx.x, i = blockIdx.x*256 + t;
  int v = (i < N_NODES) ? deg[i] : 0;
  lds[t] = v;
  __syncthreads();
  for (int off = 1; off < 256; off <<= 1){
    int x = (t >= off) ? lds[t - off] : 0;
    __syncthreads();
    lds[t] += x;
    __syncthreads();
  }
  if (i < N_NODES) loc[i] = lds[t] - v;          // local exclusive
  if (t == 255) part[blockIdx.x] = lds[255];
}

__global__ void k_scan_carry(int* __restrict__ part, int* __restrict__ carry){
  __shared__ int lds[256];
  int t = threadIdx.x;
  int v = (t < SCAN_NB) ? part[t] : 0;
  lds[t] = v;
  __syncthreads();
  for (int off = 1; off < 256; off <<= 1){
    int x = (t >= off) ? lds[t - off] : 0;
    __syncthreads();
    lds[t] += x;
    __syncthreads();
  }
  if (t < SCAN_NB) carry[t] = lds[t] - v;        // exclusive over blocks
}

__global__ void k_scan_add(const int* __restrict__ loc, const int* __restrict__ carry,
                           int* __restrict__ row_ptr){
  int i = blockIdx.x*blockDim.x + threadIdx.x;
  if (i < N_NODES) row_ptr[i] = loc[i] + carry[i >> 8];
  if (i == 0) row_ptr[N_NODES] = ET;
}

__global__ void k_fill(const int* __restrict__ ei, const int* __restrict__ row_ptr,
                       int* __restrict__ cnt, int* __restrict__ col,
                       const int* __restrict__ flag){
  int e = blockIdx.x*blockDim.x + threadIdx.x;
  if (e >= ET) return;
  int is64 = *flag;
  int s = edge_src(ei, e, is64);
  int d = edge_dst(ei, e, is64);
  int pos = atomicAdd(&cnt[d], 1);
  col[row_ptr[d] + pos] = s;
}

// ---------------- merged weight prep (one launch) ----------------
// blocks [0,256): W2 pack; [256,320): W1 pack; [320,324): wtilde
__global__ void k_wprep(const float* __restrict__ W1, const float* __restrict__ W2,
                        const float* __restrict__ as2, const float* __restrict__ ad2,
                        _Float16* __restrict__ Bp1, _Float16* __restrict__ Bp,
                        float* __restrict__ ws2, float* __restrict__ wd2){
  int b = blockIdx.x;
  int t_ = threadIdx.x;
  if (b < 256){
    int t = b*256 + t_;
    int j = t & 7, lane = (t >> 3) & 63, nt = (t >> 9) & 3, kt = t >> 11;
    int k = kt*32 + (lane >> 4)*8 + j;
    int c = nt*16 + (lane & 15);
    int h = k >> 7, kk = k & 127;
    Bp[t] = (_Float16)(0.125f * W2[kk*512 + h*64 + c]);
  } else if (b < 320){
    int t = (b - 256)*256 + t_;
    int j = t & 7, lane = (t >> 3) & 63, nt = (t >> 9) & 7, kt = t >> 12;
    int k = kt*32 + (lane >> 4)*8 + j;
    int c = nt*16 + (lane & 15);
    Bp1[t] = (_Float16)W1[k*128 + c];
  } else {
    int t = (b - 320)*256 + t_;
    int k = t >> 3, h = t & 7;
    float s = 0.f, d = 0.f;
    for (int dd = 0; dd < 64; dd++){
      float w = W2[k*512 + h*64 + dd];
      s += w * as2[h*64 + dd];
      d += w * ad2[h*64 + dd];
    }
    ws2[h*128 + k] = s;
    wd2[h*128 + k] = d;
  }
}

// ------ layer 1 GEMM via MFMA: h1 = x @ W1 (fp16 out) + fused alpha1 logits ------
__global__ void __launch_bounds__(256) k_gemm1_mfma(
    const float* __restrict__ x, const _Float16* __restrict__ Bp1,
    _Float16* __restrict__ h1,
    const float* __restrict__ as1, const float* __restrict__ ad1,
    float* __restrict__ als1, float* __restrict__ ald1){
  int tid = threadIdx.x;
  int lane = tid & 63, wv = tid >> 6;
  int n0 = blockIdx.x*64 + wv*16;
  int rowA = n0 + (lane & 15);
  int koff = (lane >> 4)*8;
  const float* xr = x + (size_t)rowA*128 + koff;
  f32x4 acc[8];
  #pragma unroll
  for (int i = 0; i < 8; i++) acc[i] = (f32x4){0.f,0.f,0.f,0.f};
  bool inb = (rowA < N_NODES);
  #pragma unroll
  for (int kt = 0; kt < 4; kt++){
    half8 af;
    if (inb){
      float4 a0 = *(const float4*)(xr + kt*32);
      float4 a1 = *(const float4*)(xr + kt*32 + 4);
      af = (half8){(_Float16)a0.x,(_Float16)a0.y,(_Float16)a0.z,(_Float16)a0.w,
                   (_Float16)a1.x,(_Float16)a1.y,(_Float16)a1.z,(_Float16)a1.w};
    } else {
      af = (half8){0,0,0,0,0,0,0,0};
    }
    #pragma unroll
    for (int nt = 0; nt < 8; nt++){
      half8 bf = *(const half8*)(Bp1 + (((kt*8 + nt)*64 + lane) << 3));
      acc[nt] = __builtin_amdgcn_mfma_f32_16x16x32_f16(af, bf, acc[nt], 0, 0, 0);
    }
  }
  int m = lane & 15, q = lane >> 4;
  int r0 = n0 + q*4;               // C/D: col=lane&15, row=(lane>>4)*4+reg  [m89]
  #pragma unroll
  for (int nt = 0; nt < 8; nt++){
    int c = nt*16 + m;
    #pragma unroll
    for (int r = 0; r < 4; r++){
      int n = r0 + r;
      if (n < N_NODES) h1[(size_t)n*128 + c] = (_Float16)acc[nt][r];
    }
  }
  // fused alpha1: lane's acc[nt][r] is channel (nt*16+m) == head nt, pos m of row r0+r
  float as1v[8], ad1v[8];
  #pragma unroll
  for (int nt = 0; nt < 8; nt++){
    as1v[nt] = as1[nt*16 + m];
    ad1v[nt] = ad1[nt*16 + m];
  }
  #pragma unroll
  for (int r = 0; r < 4; r++){
    float vs[8], vd[8];
    #pragma unroll
    for (int nt = 0; nt < 8; nt++){
      vs[nt] = acc[nt][r]*as1v[nt];
      vd[nt] = acc[nt][r]*ad1v[nt];
      #pragma unroll
      for (int off = 1; off < 16; off <<= 1){
        vs[nt] += __shfl_xor(vs[nt], off, 64);
        vd[nt] += __shfl_xor(vd[nt], off, 64);
      }
    }
    int n = r0 + r;
    if (m == r && n < N_NODES){
      float4 v0; v0.x = vs[0]; v0.y = vs[1]; v0.z = vs[2]; v0.w = vs[3];
      float4 v1; v1.x = vs[4]; v1.y = vs[5]; v1.z = vs[6]; v1.w = vs[7];
      float4 w0; w0.x = vd[0]; w0.y = vd[1]; w0.z = vd[2]; w0.w = vd[3];
      float4 w1; w1.x = vd[4]; w1.y = vd[5]; w1.z = vd[6]; w1.w = vd[7];
      *(float4*)&als1[n*8]     = v0;
      *(float4*)&als1[n*8 + 4] = v1;
      *(float4*)&ald1[n*8]     = w0;
      *(float4*)&ald1[n*8 + 4] = w1;
    }
  }
}

// ===== layer 1: two-phase softmax+agg, LDS exp+col cache, fp32 acc =====
__global__ void k_attn_agg1(const _Float16* __restrict__ h1,
    const float* __restrict__ als, const float* __restrict__ ald,
    const int* __restrict__ row_ptr, const int* __restrict__ col,
    const float* __restrict__ bias, _Float16* __restrict__ hr,
    const float* __restrict__ ws2, const float* __restrict__ wd2,
    float* __restrict__ als2, float* __restrict__ ald2){
  __shared__ _Float16 ew_s[4][CAP*8];
  __shared__ int col_s[4][CAP];
  __shared__ _Float16 ot_s[4][132];
  int tid = threadIdx.x;
  int wv = tid >> 6, lane = tid & 63;
  int n = blockIdx.x*4 + wv;              // grid exact: 12500*4 = 50000
  int beg = row_ptr[n], end = row_ptr[n+1];
  int deg = end - beg;
  int items = deg*8;
  int h = lane & 7;
  float ad = ald[n*8 + h];
  _Float16* es = ew_s[wv];
  int* cs = col_s[wv];
  float l = 0.f;
  int itc = items < CAP*8 ? items : CAP*8;
  int it = lane;
  for (; it < itc; it += 64){             // cached range: store es + col
    int e = it >> 3;
    int s = col[beg + e];
    float a = als[s*8 + h] + ad;
    a = (a > 0.f) ? a : 0.2f*a;
    float ex = __expf(a);
    es[it] = (_Float16)ex;
    if ((it & 7) == 0) cs[e] = s;
    l += ex;
  }
  for (; it < items; it += 64){           // rare overflow range
    int s = col[beg + (it >> 3)];
    float a = als[s*8 + h] + ad;
    a = (a > 0.f) ? a : 0.2f*a;
    l += __expf(a);
  }
  l += __shfl_xor(l, 8, 64);
  l += __shfl_xor(l, 16, 64);
  l += __shfl_xor(l, 32, 64);
  float inv = 1.f / (l + 1e-16f);
  __syncthreads();
  int hh0 = lane >> 3;
  float invh = __shfl(inv, hh0, 64);
  const half2v* h2p = (const half2v*)h1;
  float ax = 0.f, ay = 0.f;
  int degc = deg < CAP ? deg : CAP;
  int j = 0;
  for (; j + 7 < degc; j += 8){
    int s[8]; float w[8]; half2v v[8];
    #pragma unroll
    for (int u = 0; u < 8; u++) s[u] = cs[j + u];
    #pragma unroll
    for (int u = 0; u < 8; u++) w[u] = (float)es[(j + u)*8 + hh0] * invh;
    #pragma unroll
    for (int u = 0; u < 8; u++) v[u] = h2p[(size_t)s[u]*64 + lane];
    #pragma unroll
    for (int u = 0; u < 8; u++){ ax += w[u]*(float)v[u].x; ay += w[u]*(float)v[u].y; }
  }
  for (; j < degc; j++){
    int s = cs[j];
    float w = (float)es[j*8 + hh0] * invh;
    half2v v = h2p[(size_t)s*64 + lane];
    ax += w*(float)v.x; ay += w*(float)v.y;
  }
  float adh = ald[n*8 + hh0];
  for (; j < deg; j++){                       // rare: deg > CAP
    int s = col[beg + j];
    float a = als[s*8 + hh0] + adh;
    a = (a > 0.f) ? a : 0.2f*a;
    float w = __expf(a)*invh;
    half2v v = h2p[(size_t)s*64 + lane];
    ax += w*(float)v.x; ay += w*(float)v.y;
  }
  float2 bb = ((const float2*)bias)[lane];
  float o0 = fmaxf(ax + bb.x, 0.f);
  float o1 = fmaxf(ay + bb.y, 0.f);
  half2v oo; oo.x = (_Float16)o0; oo.y = (_Float16)o1;
  ((half2v*)hr)[(size_t)n*64 + lane] = oo;
  // fused alpha2 via LDS transpose: lane -> (head hh=lane>>3, segment seg=lane&7)
  ((half2v*)&ot_s[wv][0])[lane] = oo;     // same-wave LDS, no barrier needed
  int hh = lane >> 3, seg = lane & 7;
  const half2v* otp = (const half2v*)&ot_s[wv][0];
  const float* wsr = ws2 + hh*128 + seg*16;
  const float* wdr = wd2 + hh*128 + seg*16;
  float vs = 0.f, vd = 0.f;
  #pragma unroll
  for (int i = 0; i < 8; i++){
    half2v v = otp[seg*8 + i];
    float vx = (float)v.x, vy = (float)v.y;
    vs += vx*wsr[2*i] + vy*wsr[2*i + 1];
    vd += vx*wdr[2*i] + vy*wdr[2*i + 1];
  }
  vs += __shfl_xor(vs, 1, 64); vd += __shfl_xor(vd, 1, 64);
  vs += __shfl_xor(vs, 2, 64); vd += __shfl_xor(vd, 2, 64);
  vs += __shfl_xor(vs, 4, 64); vd += __shfl_xor(vd, 4, 64);
  if (seg == 0){
    als2[n*8 + hh] = vs;
    ald2[n*8 + hh] = vd;
  }
}

// ===== layer 2 FUSED: softmax+agg (16 waves = 16 nodes) + output MFMA GEMM =====
// Natural node order (no perm). Normalized fp16 rows -> LDS A-tile [16][LRS];
// after barrier, waves 0..3 compute out[16,64] = A @ Bp + b2 and store directly.
__global__ void __launch_bounds__(1024) k_attn_agg2(const _Float16* __restrict__ hr,
    const float* __restrict__ als, const float* __restrict__ ald,
    const int* __restrict__ row_ptr, const int* __restrict__ col,
    const _Float16* __restrict__ Bp, const float* __restrict__ b2,
    float* __restrict__ outp){
  __shared__ _Float16 ew_s[16][CAP*8];
  __shared__ int col_s[16][CAP];
  __shared__ _Float16 at[16*LRS];
  int tid = threadIdx.x;
  int wv = tid >> 6, lane = tid & 63;
  int n = blockIdx.x*16 + wv;             // grid exact: 3125*16 = 50000
  int beg = row_ptr[n], end = row_ptr[n+1];
  int deg = end - beg;
  int items = deg*8;
  int h = lane & 7;
  float ad = ald[n*8 + h];
  _Float16* es = ew_s[wv];
  int* cs = col_s[wv];
  float l = 0.f;
  int itc = items < CAP*8 ? items : CAP*8;
  int it = lane;
  for (; it < itc; it += 64){
    int e = it >> 3;
    int s = col[beg + e];
    float a = als[s*8 + h] + ad;
    a = (a > 0.f) ? a : 0.2f*a;
    float ex = __expf(a);
    es[it] = (_Float16)ex;
    if ((it & 7) == 0) cs[e] = s;
    l += ex;
  }
  for (; it < items; it += 64){
    int s = col[beg + (it >> 3)];
    float a = als[s*8 + h] + ad;
    a = (a > 0.f) ? a : 0.2f*a;
    l += __expf(a);
  }
  l += __shfl_xor(l, 8, 64);
  l += __shfl_xor(l, 16, 64);
  l += __shfl_xor(l, 32, 64);
  float inv = 1.f / (l + 1e-16f);   // for head hq = lane&7
  __syncthreads();
  int hq = lane & 7, gq = lane >> 3;
  _Float16 inv16 = (_Float16)inv;
  half2v acc[8];
  #pragma unroll
  for (int i = 0; i < 8; i++) acc[i] = (half2v){(_Float16)0.f, (_Float16)0.f};
  int degc = deg < CAP ? deg : CAP;
  int j = 0;
  for (; j + 3 < degc; j += 4){
    int s0 = cs[j], s1 = cs[j+1], s2 = cs[j+2], s3 = cs[j+3];
    _Float16 w0 = es[j*8 + hq]     * inv16;
    _Float16 w1 = es[(j+1)*8 + hq] * inv16;
    _Float16 w2 = es[(j+2)*8 + hq] * inv16;
    _Float16 w3 = es[(j+3)*8 + hq] * inv16;
    half2v w0p = {w0, w0}, w1p = {w1, w1}, w2p = {w2, w2}, w3p = {w3, w3};
    const _Float16* p0 = hr + (size_t)s0*128 + gq*16;
    const _Float16* p1 = hr + (size_t)s1*128 + gq*16;
    const _Float16* p2 = hr + (size_t)s2*128 + gq*16;
    const _Float16* p3 = hr + (size_t)s3*128 + gq*16;
    half8 va0 = *(const half8*)p0, vb0 = *(const half8*)(p0 + 8);
    half8 va1 = *(const half8*)p1, vb1 = *(const half8*)(p1 + 8);
    half8 va2 = *(const half8*)p2, vb2 = *(const half8*)(p2 + 8);
    half8 va3 = *(const half8*)p3, vb3 = *(const half8*)(p3 + 8);
    #pragma unroll
    for (int k = 0; k < 4; k++){
      acc[k]   += w0p * (half2v){va0[2*k], va0[2*k+1]};
      acc[k+4] += w0p * (half2v){vb0[2*k], vb0[2*k+1]};
      acc[k]   += w1p * (half2v){va1[2*k], va1[2*k+1]};
      acc[k+4] += w1p * (half2v){vb1[2*k], vb1[2*k+1]};
      acc[k]   += w2p * (half2v){va2[2*k], va2[2*k+1]};
      acc[k+4] += w2p * (half2v){vb2[2*k], vb2[2*k+1]};
      acc[k]   += w3p * (half2v){va3[2*k], va3[2*k+1]};
      acc[k+4] += w3p * (half2v){vb3[2*k], vb3[2*k+1]};
    }
  }
  for (; j < degc; j++){
    int s = cs[j];
    _Float16 wh = es[j*8 + hq] * inv16;
    half2v wp = {wh, wh};
    const _Float16* p = hr + (size_t)s*128 + gq*16;
    half8 va = *(const half8*)p, vb = *(const half8*)(p + 8);
    #pragma unroll
    for (int k = 0; k < 4; k++){
      acc[k]   += wp * (half2v){va[2*k], va[2*k+1]};
      acc[k+4] += wp * (half2v){vb[2*k], vb[2*k+1]};
    }
  }
  for (; j < deg; j++){                       // rare: deg > CAP
    int s = col[beg + j];
    float a = als[s*8 + hq] + ad;
    a = (a > 0.f) ? a : 0.2f*a;
    _Float16 wh = (_Float16)(__expf(a)*inv);
    half2v wp = {wh, wh};
    const _Float16* p = hr + (size_t)s*128 + gq*16;
    half8 va = *(const half8*)p, vb = *(const half8*)(p + 8);
    #pragma unroll
    for (int k = 0; k < 4; k++){
      acc[k]   += wp * (half2v){va[2*k], va[2*k+1]};
      acc[k+4] += wp * (half2v){vb[2*k], vb[2*k+1]};
    }
  }
  // write normalized row into the LDS A-tile (row = wv)
  _Float16* ar = at + wv*LRS + hq*128 + gq*16;
  half8 oa, ob;
  #pragma unroll
  for (int k = 0; k < 4; k++){
    oa[2*k] = acc[k].x;   oa[2*k+1] = acc[k].y;
    ob[2*k] = acc[k+4].x; ob[2*k+1] = acc[k+4].y;
  }
  *(half8*)ar = oa;
  *(half8*)(ar + 8) = ob;
  __syncthreads();
  if (wv >= 4) return;
  // MFMA epilogue: wave wv = output col-tile nt; A from LDS, Bp L2-hot
  int m = lane & 15, q = lane >> 4;
  const _Float16* arow = at + m*LRS + q*8;
  f32x4 cacc = (f32x4){0.f,0.f,0.f,0.f};
  #pragma unroll 4
  for (int kt = 0; kt < 32; kt++){
    half8 af = *(const half8*)(arow + kt*32);
    half8 bf = *(const half8*)(Bp + (((kt*4 + wv)*64 + lane) << 3));
    cacc = __builtin_amdgcn_mfma_f32_16x16x32_f16(af, bf, cacc, 0, 0, 0);
  }
  int c = wv*16 + m;
  float bb = b2[c];
  #pragma unroll
  for (int r = 0; r < 4; r++){
    int nrow = blockIdx.x*16 + q*4 + r;   // C/D: col=lane&15, row=(lane>>4)*4+reg [m89]
    outp[(size_t)nrow*64 + c] = cacc[r] + bb;
  }
}

extern "C" void kernel_launch(void* const* d_in, const int* in_sizes, int n_in,
                              void* d_out, int out_size, void* d_ws, size_t ws_size,
                              hipStream_t stream){
  const float* x   = (const float*)d_in[0];
  const int*   ei  = (const int*)d_in[1];
  const float* W1  = (const float*)d_in[2];
  const float* as1 = (const float*)d_in[3];
  const float* ad1 = (const float*)d_in[4];
  const float* b1  = (const float*)d_in[5];
  const float* W2  = (const float*)d_in[6];
  const float* as2 = (const float*)d_in[7];
  const float* ad2 = (const float*)d_in[8];
  const float* b2  = (const float*)d_in[9];
  float* outp = (float*)d_out;

  char* p = (char*)d_ws;
  auto alloc = [&](size_t bytes) -> void* {
    void* r = (void*)p;
    p += (bytes + 255) & ~(size_t)255;
    return r;
  };
  _Float16* h1  = (_Float16*)alloc((size_t)NPAD*128*2);          // [N,128] fp16
  _Float16* hr  = (_Float16*)alloc((size_t)N_NODES*128*2);       // [N,128] fp16
  float* als1 = (float*)alloc((size_t)N_NODES*8*4);
  float* ald1 = (float*)alloc((size_t)N_NODES*8*4);
  float* als2 = (float*)alloc((size_t)N_NODES*8*4);
  float* ald2 = (float*)alloc((size_t)N_NODES*8*4);
  int* row_ptr = (int*)alloc((size_t)(N_NODES+1)*4);
  int* deg  = (int*)alloc((size_t)N_NODES*4);
  int* cnt  = (int*)alloc((size_t)N_NODES*4);
  int* col  = (int*)alloc((size_t)ET*4);
  int* loc  = (int*)alloc((size_t)N_NODES*4);
  int* part = (int*)alloc(256*4);
  int* carry= (int*)alloc(256*4);
  int* flag = (int*)alloc(256);
  float* ws2 = (float*)alloc(1024*4);
  float* wd2 = (float*)alloc(1024*4);
  _Float16* Bp1 = (_Float16*)alloc((size_t)16384*2);
  _Float16* Bp  = (_Float16*)alloc((size_t)65536*2);

  dim3 b256(256);
  // CSR build (init incl. layout probe)
  k_init<<<(N_NODES+255)/256, b256, 0, stream>>>(ei, deg, cnt, flag);
  k_degree<<<(ET+255)/256, b256, 0, stream>>>(ei, deg, flag);
  k_scan_part<<<SCAN_NB, b256, 0, stream>>>(deg, loc, part);
  k_scan_carry<<<1, b256, 0, stream>>>(part, carry);
  k_scan_add<<<SCAN_NB, b256, 0, stream>>>(loc, carry, row_ptr);
  k_fill<<<(ET+255)/256, b256, 0, stream>>>(ei, row_ptr, cnt, col, flag);
  // merged weight prep
  k_wprep<<<324, b256, 0, stream>>>(W1, W2, as2, ad2, Bp1, Bp, ws2, wd2);

  // layer 1 (alpha1 fused into the GEMM epilogue)
  k_gemm1_mfma<<<NPAD/64, b256, 0, stream>>>(x, Bp1, h1, as1, ad1, als1, ald1);
  k_attn_agg1<<<N_NODES/4, b256, 0, stream>>>(h1, als1, ald1, row_ptr, col,
                                              b1, hr, ws2, wd2, als2, ald2);
  // layer 2: fused softmax+agg+output-GEMM
  k_attn_agg2<<<N_NODES/16, dim3(1024), 0, stream>>>(hr, als2, ald2, row_ptr, col,
                                                     Bp, b2, outp);
}